// Round 1
// baseline (3366.188 us; speedup 1.0000x reference)
//
#include <hip/hip_runtime.h>
#include <math.h>

#define S 512
#define D 512
#define FFD 1024
#define NB 16
#define NL 5

// ---------------- reduction helpers ----------------
__device__ __forceinline__ float wsum(float v){
  #pragma unroll
  for (int o = 32; o; o >>= 1) v += __shfl_down(v, o, 64);
  return v;
}
__device__ __forceinline__ float wmax(float v){
  #pragma unroll
  for (int o = 32; o; o >>= 1) v = fmaxf(v, __shfl_down(v, o, 64));
  return v;
}
// 256-thread block reduce; s points to __shared__ float[4]
__device__ __forceinline__ float bsum(float v, float* s){
  v = wsum(v);
  __syncthreads();
  if ((threadIdx.x & 63) == 0) s[threadIdx.x >> 6] = v;
  __syncthreads();
  return s[0] + s[1] + s[2] + s[3];
}
__device__ __forceinline__ float bmax(float v, float* s){
  v = wmax(v);
  __syncthreads();
  if ((threadIdx.x & 63) == 0) s[threadIdx.x >> 6] = v;
  __syncthreads();
  return fmaxf(fmaxf(s[0], s[1]), fmaxf(s[2], s[3]));
}

// ---------------- embedding gather ----------------
__global__ __launch_bounds__(256) void embed_k(const int* __restrict__ x,
    const float* __restrict__ tok, float* __restrict__ h){
  int idx = blockIdx.x * 256 + threadIdx.x;       // total = NB*S*D
  int row = idx >> 9;                             // D = 512
  int d   = idx & 511;
  h[idx] = tok[x[row] * D + d];
}

// ---------------- shared-weight GEMM: C[M,N] = A[M,K] @ W[K,N] + bias, opt relu
// 64x64 tile, BK=16, 256 threads, 4x4 microtile
__global__ __launch_bounds__(256) void gemm_bias(
    const float* __restrict__ A, const float* __restrict__ W,
    const float* __restrict__ bias, float* __restrict__ C,
    int M, int N, int K, int relu)
{
  __shared__ float As[16][72];   // transposed A tile, 72-pad keeps 16B align + no conflicts
  __shared__ float Bs[16][64];
  const int t  = threadIdx.x;
  const int tx = t & 15, ty = t >> 4;
  const int m0 = blockIdx.y * 64, n0 = blockIdx.x * 64;
  const int la_r = t >> 2, la_c = (t & 3) << 2;   // A: 64 rows x 16 cols, float4
  const int lb_r = t >> 4, lb_c = (t & 15) << 2;  // W: 16 rows x 64 cols, float4
  float acc[4][4] = {};
  for (int k0 = 0; k0 < K; k0 += 16){
    float4 a4 = *(const float4*)&A[(size_t)(m0 + la_r) * K + k0 + la_c];
    As[la_c + 0][la_r] = a4.x; As[la_c + 1][la_r] = a4.y;
    As[la_c + 2][la_r] = a4.z; As[la_c + 3][la_r] = a4.w;
    *(float4*)&Bs[lb_r][lb_c] = *(const float4*)&W[(size_t)(k0 + lb_r) * N + n0 + lb_c];
    __syncthreads();
    #pragma unroll
    for (int kk = 0; kk < 16; kk++){
      float4 av = *(const float4*)&As[kk][ty << 2];
      float4 bv = *(const float4*)&Bs[kk][tx << 2];
      float a[4] = {av.x, av.y, av.z, av.w};
      float b[4] = {bv.x, bv.y, bv.z, bv.w};
      #pragma unroll
      for (int i = 0; i < 4; i++)
        #pragma unroll
        for (int j = 0; j < 4; j++) acc[i][j] = fmaf(a[i], b[j], acc[i][j]);
    }
    __syncthreads();
  }
  float4 bb = *(const float4*)&bias[n0 + (tx << 2)];
  float bvals[4] = {bb.x, bb.y, bb.z, bb.w};
  #pragma unroll
  for (int i = 0; i < 4; i++){
    int m = m0 + (ty << 2) + i;
    float ov[4];
    #pragma unroll
    for (int j = 0; j < 4; j++){
      float vv = acc[i][j] + bvals[j];
      if (relu) vv = fmaxf(vv, 0.f);
      ov[j] = vv;
    }
    *(float4*)&C[(size_t)m * N + n0 + (tx << 2)] =
        make_float4(ov[0], ov[1], ov[2], ov[3]);
  }
}

// ---------------- qrel[b,i,c] = q[b,i,:] . rel_emb[c,:]  (c = 0..10, stride 16)
__global__ __launch_bounds__(256) void qrel_k(
    const float* __restrict__ q, const float* __restrict__ rel,
    float* __restrict__ qr)
{
  const int w = threadIdx.x >> 6, lane = threadIdx.x & 63;
  const int row = blockIdx.x * 4 + w;             // b*S + i
  const float* qp = q + (size_t)row * D + lane * 8;
  float qv[8];
  #pragma unroll
  for (int e = 0; e < 8; e++) qv[e] = qp[e];
  #pragma unroll
  for (int c = 0; c < 11; c++){
    const float* rp = rel + c * D + lane * 8;
    float sacc = 0.f;
    #pragma unroll
    for (int e = 0; e < 8; e++) sacc = fmaf(qv[e], rp[e], sacc);
    sacc = wsum(sacc);
    if (lane == 0) qr[(size_t)row * 16 + c] = sacc;
  }
}

// ---------------- scores[b,i,j] = (q.k)/512 + qrel[b,i,min(|i-j|,10)]/sqrt(512), causal
// batched NT GEMM, 64x64 tiles; fully-masked tiles skipped
__global__ __launch_bounds__(256) void scores_nt(
    const float* __restrict__ q, const float* __restrict__ kmat,
    const float* __restrict__ qrel, float* __restrict__ sc)
{
  const int b  = blockIdx.z;
  const int i0 = blockIdx.y * 64, j0 = blockIdx.x * 64;
  if (j0 > i0 + 63) return;                       // entire tile above diagonal
  __shared__ float As[16][72];
  __shared__ float Bs[16][72];
  const int t  = threadIdx.x;
  const int tx = t & 15, ty = t >> 4;
  const int lr = t >> 2, lc = (t & 3) << 2;
  const float* qb = q    + (size_t)b * S * D;
  const float* kb = kmat + (size_t)b * S * D;
  float acc[4][4] = {};
  for (int k0 = 0; k0 < D; k0 += 16){
    float4 a4 = *(const float4*)&qb[(size_t)(i0 + lr) * D + k0 + lc];
    As[lc + 0][lr] = a4.x; As[lc + 1][lr] = a4.y;
    As[lc + 2][lr] = a4.z; As[lc + 3][lr] = a4.w;
    float4 b4 = *(const float4*)&kb[(size_t)(j0 + lr) * D + k0 + lc];
    Bs[lc + 0][lr] = b4.x; Bs[lc + 1][lr] = b4.y;
    Bs[lc + 2][lr] = b4.z; Bs[lc + 3][lr] = b4.w;
    __syncthreads();
    #pragma unroll
    for (int kq = 0; kq < 16; kq++){
      float4 av = *(const float4*)&As[kq][ty << 2];
      float4 bv = *(const float4*)&Bs[kq][tx << 2];
      float a[4] = {av.x, av.y, av.z, av.w};
      float bvv[4] = {bv.x, bv.y, bv.z, bv.w};
      #pragma unroll
      for (int i = 0; i < 4; i++)
        #pragma unroll
        for (int j = 0; j < 4; j++) acc[i][j] = fmaf(a[i], bvv[j], acc[i][j]);
    }
    __syncthreads();
  }
  const float s1 = 0.044194173824159216f;   // 1/sqrt(512)
  const float s2 = 1.0f / 512.0f;           // double-scale per reference bug
  #pragma unroll
  for (int ii = 0; ii < 4; ii++){
    int i = i0 + (ty << 2) + ii;
    float* row = sc + ((size_t)b * S + i) * S;
    const float* qrp = qrel + ((size_t)b * S + i) * 16;
    #pragma unroll
    for (int jj = 0; jj < 4; jj++){
      int j = j0 + (tx << 2) + jj;
      float val;
      if (j <= i){
        int dd = i - j; if (dd > 10) dd = 10;
        val = acc[ii][jj] * s2 + qrp[dd] * s1;
      } else {
        val = -1e9f;
      }
      row[j] = val;
    }
  }
}

// ---------------- row softmax over j<=i, zeros above diagonal
__global__ __launch_bounds__(256) void softmax_k(float* __restrict__ sc){
  __shared__ float red[4];
  const int row = blockIdx.x;                     // b*S + i
  const int i   = row & (S - 1);
  const int n   = i + 1;
  float* sr = sc + (size_t)row * S;
  const int t = threadIdx.x;
  float m = -1e30f;
  for (int j = t; j < n; j += 256) m = fmaxf(m, sr[j]);
  m = bmax(m, red);
  float sum = 0.f;
  for (int j = t; j < n; j += 256){
    float e = __expf(sr[j] - m);
    sr[j] = e;
    sum += e;
  }
  sum = bsum(sum, red);
  float inv = 1.0f / sum;
  for (int j = t; j < S; j += 256)
    sr[j] = (j < n) ? sr[j] * inv : 0.f;
}

// ---------------- ctx[b,i,d] = sum_j p[b,i,j] v[b,j,d]; K-loop stops at diagonal tile
__global__ __launch_bounds__(256) void ctx_nn(
    const float* __restrict__ p, const float* __restrict__ v,
    float* __restrict__ ctx)
{
  const int b  = blockIdx.z;
  const int i0 = blockIdx.y * 64, d0 = blockIdx.x * 64;
  __shared__ float As[16][72];
  __shared__ float Bs[16][64];
  const int t  = threadIdx.x;
  const int tx = t & 15, ty = t >> 4;
  const int la_r = t >> 2, la_c = (t & 3) << 2;
  const int lb_r = t >> 4, lb_c = (t & 15) << 2;
  const float* pb = p + (size_t)b * S * S;
  const float* vb = v + (size_t)b * S * D;
  float acc[4][4] = {};
  const int kmax = i0 + 64;                       // p is 0 above the diagonal
  for (int k0 = 0; k0 < kmax; k0 += 16){
    float4 a4 = *(const float4*)&pb[(size_t)(i0 + la_r) * S + k0 + la_c];
    As[la_c + 0][la_r] = a4.x; As[la_c + 1][la_r] = a4.y;
    As[la_c + 2][la_r] = a4.z; As[la_c + 3][la_r] = a4.w;
    *(float4*)&Bs[lb_r][lb_c] = *(const float4*)&vb[(size_t)(k0 + lb_r) * D + d0 + lb_c];
    __syncthreads();
    #pragma unroll
    for (int kk = 0; kk < 16; kk++){
      float4 av = *(const float4*)&As[kk][ty << 2];
      float4 bv = *(const float4*)&Bs[kk][tx << 2];
      float a[4] = {av.x, av.y, av.z, av.w};
      float bvv[4] = {bv.x, bv.y, bv.z, bv.w};
      #pragma unroll
      for (int i = 0; i < 4; i++)
        #pragma unroll
        for (int j = 0; j < 4; j++) acc[i][j] = fmaf(a[i], bvv[j], acc[i][j]);
    }
    __syncthreads();
  }
  #pragma unroll
  for (int ii = 0; ii < 4; ii++){
    int i = i0 + (ty << 2) + ii;
    *(float4*)&ctx[((size_t)b * S + i) * D + d0 + (tx << 2)] =
        make_float4(acc[ii][0], acc[ii][1], acc[ii][2], acc[ii][3]);
  }
}

// ---------------- h = LayerNorm(h + y) * g + b   (in place on h)
__global__ __launch_bounds__(256) void add_ln_k(
    float* __restrict__ h, const float* __restrict__ y,
    const float* __restrict__ g, const float* __restrict__ be)
{
  __shared__ float red[4];
  const int row = blockIdx.x;
  float* hr = h + (size_t)row * D;
  const float* yr = y + (size_t)row * D;
  const int t = threadIdx.x;
  float v0 = hr[t]       + yr[t];
  float v1 = hr[t + 256] + yr[t + 256];
  float mu = bsum(v0 + v1, red) * (1.0f / 512.0f);
  float d0 = v0 - mu, d1 = v1 - mu;
  float var = bsum(d0 * d0 + d1 * d1, red) * (1.0f / 512.0f);
  float r = rsqrtf(var + 1e-5f);
  hr[t]       = d0 * r * g[t]       + be[t];
  hr[t + 256] = d1 * r * g[t + 256] + be[t + 256];
}

// ---------------- driver ----------------
extern "C" void kernel_launch(void* const* d_in, const int* in_sizes, int n_in,
                              void* d_out, int out_size, void* d_ws, size_t ws_size,
                              hipStream_t stream)
{
  const int*   x   = (const int*)  d_in[0];
  const float* tok = (const float*)d_in[1];
  const float* rel = (const float*)d_in[2];
  const float* Wq  = (const float*)d_in[3];  const float* bq = (const float*)d_in[4];
  const float* Wk  = (const float*)d_in[5];  const float* bk = (const float*)d_in[6];
  const float* Wv  = (const float*)d_in[7];  const float* bv = (const float*)d_in[8];
  const float* Wo  = (const float*)d_in[9];  const float* bo = (const float*)d_in[10];
  const float* W1  = (const float*)d_in[11]; const float* b1 = (const float*)d_in[12];
  const float* W2  = (const float*)d_in[13]; const float* b2 = (const float*)d_in[14];
  const float* g1  = (const float*)d_in[15]; const float* be1 = (const float*)d_in[16];
  const float* g2  = (const float*)d_in[17]; const float* be2 = (const float*)d_in[18];

  float* h = (float*)d_out;                       // [NB*S, D], lives in d_out

  // workspace layout (bytes):
  //   q      : [0,   16M)   -> later reused as ctx
  //   k      : [16M, 32M)   -> later x_att, then ff_out
  //   v+sc   : [32M, 64M)   -> v:[32,48) scores:[48,64); later ffmid spans [32,64)
  //   qrel   : [64M, 64.5M)
  char* ws = (char*)d_ws;
  const size_t MB16 = (size_t)NB * S * D * 4;     // 16 MiB
  float* q      = (float*)(ws);
  float* kb     = (float*)(ws + MB16);
  float* vbuf   = (float*)(ws + 2 * MB16);
  float* scores = (float*)(ws + 3 * MB16);
  float* ffmid  = (float*)(ws + 2 * MB16);        // overlaps v+scores (dead by then)
  float* qrelb  = (float*)(ws + 4 * MB16);
  (void)in_sizes; (void)n_in; (void)out_size; (void)ws_size;

  const int M = NB * S;                           // 8192
  embed_k<<<(size_t)M * D / 256, 256, 0, stream>>>(x, tok, h);

  for (int l = 0; l < NL; l++){
    const float* wq = Wq + (size_t)l * D * D;
    const float* wk = Wk + (size_t)l * D * D;
    const float* wv = Wv + (size_t)l * D * D;
    const float* wo = Wo + (size_t)l * D * D;
    const float* w1 = W1 + (size_t)l * D * FFD;
    const float* w2 = W2 + (size_t)l * FFD * D;

    gemm_bias<<<dim3(D / 64, M / 64), 256, 0, stream>>>(h, wq, bq + l * D, q,    M, D, D, 0);
    gemm_bias<<<dim3(D / 64, M / 64), 256, 0, stream>>>(h, wk, bk + l * D, kb,   M, D, D, 0);
    gemm_bias<<<dim3(D / 64, M / 64), 256, 0, stream>>>(h, wv, bv + l * D, vbuf, M, D, D, 0);

    qrel_k<<<M / 4, 256, 0, stream>>>(q, rel, qrelb);
    scores_nt<<<dim3(S / 64, S / 64, NB), 256, 0, stream>>>(q, kb, qrelb, scores);
    softmax_k<<<M, 256, 0, stream>>>(scores);
    ctx_nn<<<dim3(D / 64, S / 64, NB), 256, 0, stream>>>(scores, vbuf, q);  // ctx -> q

    gemm_bias<<<dim3(D / 64, M / 64), 256, 0, stream>>>(q, wo, bo + l * D, kb, M, D, D, 0);
    add_ln_k<<<M, 256, 0, stream>>>(h, kb, g1 + l * D, be1 + l * D);

    gemm_bias<<<dim3(FFD / 64, M / 64), 256, 0, stream>>>(h, w1, b1 + l * FFD, ffmid, M, FFD, D, 1);
    gemm_bias<<<dim3(D / 64, M / 64), 256, 0, stream>>>(ffmid, w2, b2 + l * D, kb, M, D, FFD, 0);
    add_ln_k<<<M, 256, 0, stream>>>(h, kb, g2 + l * D, be2 + l * D);
  }
}

// Round 2
// 915.655 us; speedup vs baseline: 3.6763x; 3.6763x over previous
//
#include <hip/hip_runtime.h>
#include <math.h>

#define S 512
#define D 512
#define FFD 1024
#define NB 16
#define NL 5

typedef __attribute__((ext_vector_type(8))) short bf16x8;
typedef __attribute__((ext_vector_type(4))) float f32x4;

// ---------------- bf16 helpers ----------------
__device__ __forceinline__ short f2bf(float f){
  union { float f; unsigned u; } c; c.f = f;
  unsigned r = c.u + 0x7FFFu + ((c.u >> 16) & 1u);   // RNE
  return (short)(r >> 16);
}
__device__ __forceinline__ float bf2f(short s){
  union { unsigned u; float f; } c; c.u = ((unsigned)(unsigned short)s) << 16;
  return c.f;
}

// async global->LDS, 16B per lane; lds ptr must be wave-uniform base
__device__ __forceinline__ void gload16(const void* g, void* l){
  __builtin_amdgcn_global_load_lds(
      (const __attribute__((address_space(1))) void*)g,
      (__attribute__((address_space(3))) void*)l, 16, 0, 0);
}

// ---------------- reduction helpers ----------------
__device__ __forceinline__ float wsum(float v){
  #pragma unroll
  for (int o = 32; o; o >>= 1) v += __shfl_down(v, o, 64);
  return v;
}
__device__ __forceinline__ float wmax(float v){
  #pragma unroll
  for (int o = 32; o; o >>= 1) v = fmaxf(v, __shfl_down(v, o, 64));
  return v;
}
__device__ __forceinline__ float bsum(float v, float* s){
  v = wsum(v);
  __syncthreads();
  if ((threadIdx.x & 63) == 0) s[threadIdx.x >> 6] = v;
  __syncthreads();
  return s[0] + s[1] + s[2] + s[3];
}
__device__ __forceinline__ float bmax(float v, float* s){
  v = wmax(v);
  __syncthreads();
  if ((threadIdx.x & 63) == 0) s[threadIdx.x >> 6] = v;
  __syncthreads();
  return fmaxf(fmaxf(s[0], s[1]), fmaxf(s[2], s[3]));
}

// ---------------- embedding gather (f32 h + bf16 hb) ----------------
__global__ __launch_bounds__(256) void embed_k(const int* __restrict__ x,
    const float* __restrict__ tok, float* __restrict__ h, short* __restrict__ hb){
  int idx = blockIdx.x * 256 + threadIdx.x;
  int row = idx >> 9;
  int d   = idx & 511;
  float v = tok[x[row] * D + d];
  h[idx]  = v;
  hb[idx] = f2bf(v);
}

// ---------------- weight transpose + bf16 cast: in[K][N] f32 -> out[N][K] bf16
__global__ __launch_bounds__(256) void wtrans_k(
    const float* __restrict__ Wq, const float* __restrict__ Wk,
    const float* __restrict__ Wv, const float* __restrict__ Wo,
    const float* __restrict__ W1, const float* __restrict__ W2,
    short* __restrict__ WqT, short* __restrict__ WkT,
    short* __restrict__ WvT, short* __restrict__ WoT,
    short* __restrict__ W1T, short* __restrict__ W2T)
{
  __shared__ float tl[64][65];
  int id = blockIdx.x;
  const float* src; short* dst; int K, N, tk, tn;
  if (id < 1280){
    int mat = id / 320, r = id % 320, lay = r / 64, tt = r % 64;
    tk = tt >> 3; tn = tt & 7; K = 512; N = 512;
    const float* s;
    short* d;
    if (mat == 0){ s = Wq; d = WqT; } else if (mat == 1){ s = Wk; d = WkT; }
    else if (mat == 2){ s = Wv; d = WvT; } else { s = Wo; d = WoT; }
    src = s + (size_t)lay * 262144; dst = d + (size_t)lay * 262144;
  } else if (id < 1920){
    int r = id - 1280, lay = r / 128, tt = r % 128;
    tk = tt >> 4; tn = tt & 15; K = 512; N = 1024;
    src = W1 + (size_t)lay * 524288; dst = W1T + (size_t)lay * 524288;
  } else {
    int r = id - 1920, lay = r / 128, tt = r % 128;
    tk = tt >> 3; tn = tt & 7; K = 1024; N = 512;
    src = W2 + (size_t)lay * 524288; dst = W2T + (size_t)lay * 524288;
  }
  const int k0 = tk * 64, n0 = tn * 64;
  const int t = threadIdx.x;
  const int lr = t >> 4, lc = (t & 15) * 4;
  #pragma unroll
  for (int s = 0; s < 4; s++){
    int row = lr + s * 16;
    float4 v = *(const float4*)&src[(size_t)(k0 + row) * N + n0 + lc];
    tl[row][lc + 0] = v.x; tl[row][lc + 1] = v.y;
    tl[row][lc + 2] = v.z; tl[row][lc + 3] = v.w;
  }
  __syncthreads();
  const int nr8 = t >> 3, kc8 = (t & 7) * 8;
  #pragma unroll
  for (int s = 0; s < 2; s++){
    int nr = nr8 + s * 32;
    bf16x8 o;
    #pragma unroll
    for (int e = 0; e < 8; e++) o[e] = f2bf(tl[kc8 + e][nr]);
    *(bf16x8*)&dst[(size_t)(n0 + nr) * K + k0 + kc8] = o;
  }
}

// ---------------- bf16 batched transpose: in[b][S][D] -> out[b][D][S] ----------------
__global__ __launch_bounds__(256) void vtrans_k(const short* __restrict__ in,
                                                short* __restrict__ out){
  __shared__ short tl[64][72];
  const int b = blockIdx.z;
  const int j0 = blockIdx.y * 64, d0 = blockIdx.x * 64;
  in  += (size_t)b * S * D;
  out += (size_t)b * D * S;
  const int t = threadIdx.x;
  const int r = t >> 3, c8 = (t & 7) * 8;
  #pragma unroll
  for (int s = 0; s < 2; s++){
    int row = r + s * 32;
    *(bf16x8*)&tl[row][c8] = *(const bf16x8*)&in[(size_t)(j0 + row) * D + d0 + c8];
  }
  __syncthreads();
  #pragma unroll
  for (int s = 0; s < 2; s++){
    int dr = r + s * 32;
    bf16x8 o;
    #pragma unroll
    for (int e = 0; e < 8; e++) o[e] = tl[c8 + e][dr];
    *(bf16x8*)&out[(size_t)(d0 + dr) * S + j0 + c8] = o;
  }
}

// ---------------- MFMA NT mainloop: C128x128 tile, BK=32, 2-phase dbuf ----------------
__device__ __forceinline__ void mfma_mainloop(
    const short* __restrict__ Abase, const short* __restrict__ Bbase,
    const int K, const int nk, short* As, short* Bs, f32x4 acc[4][4])
{
  const int t = threadIdx.x;
  const int l = t & 63;
  const int w = t >> 6;
  const int wm = (w >> 1) * 64;
  const int wn = (w & 1) * 64;
  const int srow = t >> 2;             // 0..63 within half-tile
  const int scol = (t & 3) * 8;        // bf16 elements
  const short* ga = Abase + (size_t)srow * K + scol;
  const short* gb = Bbase + (size_t)srow * K + scol;
  char* lA = (char*)As + w * 1024;     // wave-uniform LDS base
  char* lB = (char*)Bs + w * 1024;
  const size_t half = (size_t)64 * K;

  // prologue: stage k-step 0 into buffer 0
  gload16(ga,        lA);
  gload16(ga + half, lA + 4096);
  gload16(gb,        lB);
  gload16(gb + half, lB + 4096);
  __syncthreads();

  const int kc = (l >> 4) * 8;
  for (int ks = 0; ks < nk; ks++){
    const int cur = ks & 1;
    if (ks + 1 < nk){                  // prefetch next tile into other buffer
      const int nxt = cur ^ 1;
      const short* ga2 = ga + (size_t)(ks + 1) * 32;
      const short* gb2 = gb + (size_t)(ks + 1) * 32;
      gload16(ga2,        lA + nxt * 8192);
      gload16(ga2 + half, lA + nxt * 8192 + 4096);
      gload16(gb2,        lB + nxt * 8192);
      gload16(gb2 + half, lB + nxt * 8192 + 4096);
    }
    const short* Ab = As + cur * 4096;
    const short* Bb = Bs + cur * 4096;
    bf16x8 af[4], bfr[4];
    #pragma unroll
    for (int m = 0; m < 4; m++)
      af[m] = *(const bf16x8*)&Ab[(wm + m * 16 + (l & 15)) * 32 + kc];
    #pragma unroll
    for (int n = 0; n < 4; n++)
      bfr[n] = *(const bf16x8*)&Bb[(wn + n * 16 + (l & 15)) * 32 + kc];
    #pragma unroll
    for (int m = 0; m < 4; m++)
      #pragma unroll
      for (int n = 0; n < 4; n++)
        acc[m][n] = __builtin_amdgcn_mfma_f32_16x16x32_bf16(af[m], bfr[n], acc[m][n], 0, 0, 0);
    __syncthreads();
  }
}

// MODE: 0 f32+bias, 1 bf16+bias, 2 bf16+bias+relu, 3 scores epilogue, 4 PV (bf16, kmax)
template<int MODE>
__global__ __launch_bounds__(256) void mm_nt(
    const short* __restrict__ A, const short* __restrict__ B,
    const float* __restrict__ bias, void* __restrict__ C,
    const float* __restrict__ qrel,
    int M, int N, int K, long batA, long batB, long batC)
{
  const int b  = blockIdx.z;
  const int m0 = blockIdx.y * 128, n0 = blockIdx.x * 128;
  if (MODE == 3 && n0 > m0) return;    // tile fully above causal diagonal
  __shared__ short As[2 * 128 * 32];
  __shared__ short Bs[2 * 128 * 32];
  int nk = K / 32;
  if (MODE == 4){ int km = (m0 + 128) / 32; nk = km < nk ? km : nk; }

  f32x4 acc[4][4];
  const f32x4 z = {0.f, 0.f, 0.f, 0.f};
  #pragma unroll
  for (int m = 0; m < 4; m++)
    #pragma unroll
    for (int n = 0; n < 4; n++) acc[m][n] = z;

  mfma_mainloop(A + (size_t)b * batA + (size_t)m0 * K,
                B + (size_t)b * batB + (size_t)n0 * K,
                K, nk, As, Bs, acc);

  const int t = threadIdx.x, l = t & 63, w = t >> 6;
  const int wm = (w >> 1) * 64, wn = (w & 1) * 64;
  const size_t cbase = (size_t)b * batC;
  #pragma unroll
  for (int m = 0; m < 4; m++){
    const int rbase = m0 + wm + m * 16 + (l >> 4) * 4;
    #pragma unroll
    for (int n = 0; n < 4; n++){
      const int col = n0 + wn + n * 16 + (l & 15);
      #pragma unroll
      for (int r = 0; r < 4; r++){
        const int row = rbase + r;
        float v = acc[m][n][r];
        if (MODE == 0 || MODE == 1 || MODE == 2) v += bias[col];
        if (MODE == 2) v = fmaxf(v, 0.f);
        if (MODE == 3){
          float sv;
          if (col <= row){
            int dd = row - col; if (dd > 10) dd = 10;
            sv = v * (1.0f / 512.0f)
               + qrel[((size_t)b * S + row) * 16 + dd] * 0.044194173824159216f;
          } else sv = -1e9f;
          ((float*)C)[cbase + (size_t)row * N + col] = sv;
        } else if (MODE == 0){
          ((float*)C)[cbase + (size_t)row * N + col] = v;
        } else if (MODE == 4){
          ((short*)C)[cbase + (size_t)row * N + col] = f2bf(v);
        } else {
          ((short*)C)[cbase + (size_t)row * N + col] = f2bf(v);
        }
      }
    }
  }
}

// ---------------- qrel[b,i,c] = q[b,i,:] . rel_emb[c,:] (bf16 q) ----------------
__global__ __launch_bounds__(256) void qrel_k(
    const short* __restrict__ q, const float* __restrict__ rel,
    float* __restrict__ qr)
{
  const int w = threadIdx.x >> 6, lane = threadIdx.x & 63;
  const int row = blockIdx.x * 4 + w;
  bf16x8 q8 = *(const bf16x8*)&q[(size_t)row * D + lane * 8];
  float qv[8];
  #pragma unroll
  for (int e = 0; e < 8; e++) qv[e] = bf2f(q8[e]);
  #pragma unroll
  for (int c = 0; c < 11; c++){
    const float* rp = rel + c * D + lane * 8;
    float s = 0.f;
    #pragma unroll
    for (int e = 0; e < 8; e++) s = fmaf(qv[e], rp[e], s);
    s = wsum(s);
    if (lane == 0) qr[(size_t)row * 16 + c] = s;
  }
}

// ---------------- softmax row (f32 in) -> bf16 p, zeros above diagonal ----------------
__global__ __launch_bounds__(256) void softmax_k(const float* __restrict__ sc,
                                                 short* __restrict__ p){
  __shared__ float red[4];
  const int row = blockIdx.x;
  const int i = row & (S - 1);
  const int n = i + 1;
  const float* sr = sc + (size_t)row * S;
  short* pr = p + (size_t)row * S;
  const int t = threadIdx.x;
  float a = (t < n)       ? sr[t]       : -1e30f;
  float c = (t + 256 < n) ? sr[t + 256] : -1e30f;
  float m = bmax(fmaxf(a, c), red);
  float e0 = (t < n)       ? __expf(a - m) : 0.f;
  float e1 = (t + 256 < n) ? __expf(c - m) : 0.f;
  float sum = bsum(e0 + e1, red);
  float inv = 1.0f / sum;
  pr[t]       = f2bf(e0 * inv);
  pr[t + 256] = f2bf(e1 * inv);
}

// ---------------- h = LN(h + y); also emit bf16 copy ----------------
__global__ __launch_bounds__(256) void add_ln_k(
    float* __restrict__ h, const float* __restrict__ y,
    const float* __restrict__ g, const float* __restrict__ be,
    short* __restrict__ hb)
{
  __shared__ float red[4];
  const int row = blockIdx.x;
  float* hr = h + (size_t)row * D;
  const float* yr = y + (size_t)row * D;
  short* hbr = hb + (size_t)row * D;
  const int t = threadIdx.x;
  float v0 = hr[t]       + yr[t];
  float v1 = hr[t + 256] + yr[t + 256];
  float mu = bsum(v0 + v1, red) * (1.0f / 512.0f);
  float d0 = v0 - mu, d1 = v1 - mu;
  float var = bsum(d0 * d0 + d1 * d1, red) * (1.0f / 512.0f);
  float rcp = rsqrtf(var + 1e-5f);
  float o0 = d0 * rcp * g[t]       + be[t];
  float o1 = d1 * rcp * g[t + 256] + be[t + 256];
  hr[t]        = o0;
  hr[t + 256]  = o1;
  hbr[t]       = f2bf(o0);
  hbr[t + 256] = f2bf(o1);
}

// ---------------- driver ----------------
extern "C" void kernel_launch(void* const* d_in, const int* in_sizes, int n_in,
                              void* d_out, int out_size, void* d_ws, size_t ws_size,
                              hipStream_t stream)
{
  const int*   x   = (const int*)  d_in[0];
  const float* tok = (const float*)d_in[1];
  const float* rel = (const float*)d_in[2];
  const float* Wq  = (const float*)d_in[3];  const float* bq = (const float*)d_in[4];
  const float* Wk  = (const float*)d_in[5];  const float* bk = (const float*)d_in[6];
  const float* Wv  = (const float*)d_in[7];  const float* bv = (const float*)d_in[8];
  const float* Wo  = (const float*)d_in[9];  const float* bo = (const float*)d_in[10];
  const float* W1  = (const float*)d_in[11]; const float* b1 = (const float*)d_in[12];
  const float* W2  = (const float*)d_in[13]; const float* b2 = (const float*)d_in[14];
  const float* g1  = (const float*)d_in[15]; const float* be1 = (const float*)d_in[16];
  const float* g2  = (const float*)d_in[17]; const float* be2 = (const float*)d_in[18];
  (void)in_sizes; (void)n_in; (void)out_size; (void)ws_size;

  float* h = (float*)d_out;                    // [8192][512] f32

  char* ws = (char*)d_ws;
  const size_t MB = 1 << 20;
  short* hb    = (short*)(ws);                 // 8MB bf16 h
  short* qb    = (short*)(ws + 8 * MB);        // 8MB
  short* kbb   = (short*)(ws + 16 * MB);       // 8MB
  short* vTb   = (short*)(ws + 24 * MB);       // 8MB
  char*  big   = ws + 32 * MB;                 // 16MB: v / scores / xatt / ffmid
  float* qrelb = (float*)(ws + 48 * MB);       // 0.5MB
  char*  wb    = ws + 49 * MB;                 // 20MB bf16 transposed weights
  short* WqT = (short*)(wb);
  short* WkT = (short*)(wb + (size_t)2560 * 1024);
  short* WvT = (short*)(wb + (size_t)2 * 2560 * 1024);
  short* WoT = (short*)(wb + (size_t)3 * 2560 * 1024);
  short* W1T = (short*)(wb + (size_t)4 * 2560 * 1024);
  short* W2T = (short*)(wb + (size_t)4 * 2560 * 1024 + 5 * MB);

  short* vb     = (short*)big;
  float* scores = (float*)big;
  float* xatt   = (float*)big;
  short* ffmid  = (short*)big;
  short* p      = qb;                          // reuse (q dead after scores)
  short* ctx    = kbb;                         // reuse (k dead after scores)
  float* ffout  = (float*)qb;                  // 16MB spanning qb+kbb

  const int M = NB * S;                        // 8192

  wtrans_k<<<2560, 256, 0, stream>>>(Wq, Wk, Wv, Wo, W1, W2,
                                     WqT, WkT, WvT, WoT, W1T, W2T);
  embed_k<<<(size_t)M * D / 256, 256, 0, stream>>>(x, tok, h, hb);

  for (int l = 0; l < NL; l++){
    const short* wqt = WqT + (size_t)l * 262144;
    const short* wkt = WkT + (size_t)l * 262144;
    const short* wvt = WvT + (size_t)l * 262144;
    const short* wot = WoT + (size_t)l * 262144;
    const short* w1t = W1T + (size_t)l * 524288;
    const short* w2t = W2T + (size_t)l * 524288;

    mm_nt<1><<<dim3(4, 64, 1), 256, 0, stream>>>(hb, wqt, bq + l * D, qb,  nullptr, M, D, D, 0, 0, 0);
    mm_nt<1><<<dim3(4, 64, 1), 256, 0, stream>>>(hb, wkt, bk + l * D, kbb, nullptr, M, D, D, 0, 0, 0);
    mm_nt<1><<<dim3(4, 64, 1), 256, 0, stream>>>(hb, wvt, bv + l * D, vb,  nullptr, M, D, D, 0, 0, 0);

    vtrans_k<<<dim3(D / 64, S / 64, NB), 256, 0, stream>>>(vb, vTb);
    qrel_k<<<M / 4, 256, 0, stream>>>(qb, rel, qrelb);

    mm_nt<3><<<dim3(4, 4, NB), 256, 0, stream>>>(qb, kbb, nullptr, scores, qrelb,
                                                 S, S, D, (long)S * D, (long)S * D, (long)S * S);
    softmax_k<<<M, 256, 0, stream>>>(scores, p);
    mm_nt<4><<<dim3(4, 4, NB), 256, 0, stream>>>(p, vTb, nullptr, ctx, nullptr,
                                                 S, D, S, (long)S * S, (long)D * S, (long)S * D);

    mm_nt<0><<<dim3(4, 64, 1), 256, 0, stream>>>(ctx, wot, bo + l * D, xatt, nullptr, M, D, D, 0, 0, 0);
    add_ln_k<<<M, 256, 0, stream>>>(h, xatt, g1 + l * D, be1 + l * D, hb);

    mm_nt<2><<<dim3(8, 64, 1), 256, 0, stream>>>(hb, w1t, b1 + l * FFD, ffmid, nullptr, M, FFD, D, 0, 0, 0);
    mm_nt<0><<<dim3(4, 64, 1), 256, 0, stream>>>(ffmid, w2t, b2 + l * D, ffout, nullptr, M, D, FFD, 0, 0, 0);
    add_ln_k<<<M, 256, 0, stream>>>(h, ffout, g2 + l * D, be2 + l * D, hb);
  }
}

// Round 3
// 776.649 us; speedup vs baseline: 4.3342x; 1.1790x over previous
//
#include <hip/hip_runtime.h>
#include <math.h>

#define S 512
#define D 512
#define FFD 1024
#define NB 16
#define NL 5

typedef __attribute__((ext_vector_type(8))) short bf16x8;
typedef __attribute__((ext_vector_type(4))) float f32x4;

// ---------------- bf16 helpers ----------------
__device__ __forceinline__ short f2bf(float f){
  union { float f; unsigned u; } c; c.f = f;
  unsigned r = c.u + 0x7FFFu + ((c.u >> 16) & 1u);   // RNE
  return (short)(r >> 16);
}
__device__ __forceinline__ float bf2f(short s){
  union { unsigned u; float f; } c; c.u = ((unsigned)(unsigned short)s) << 16;
  return c.f;
}

// async global->LDS, 16B per lane; lds ptr must be wave-uniform base
__device__ __forceinline__ void gload16(const void* g, void* l){
  __builtin_amdgcn_global_load_lds(
      (const __attribute__((address_space(1))) void*)g,
      (__attribute__((address_space(3))) void*)l, 16, 0, 0);
}

// ---------------- reduction helpers ----------------
__device__ __forceinline__ float wsum(float v){
  #pragma unroll
  for (int o = 32; o; o >>= 1) v += __shfl_down(v, o, 64);
  return v;
}
__device__ __forceinline__ float wmax(float v){
  #pragma unroll
  for (int o = 32; o; o >>= 1) v = fmaxf(v, __shfl_down(v, o, 64));
  return v;
}
__device__ __forceinline__ float bsum(float v, float* s){
  v = wsum(v);
  __syncthreads();
  if ((threadIdx.x & 63) == 0) s[threadIdx.x >> 6] = v;
  __syncthreads();
  return s[0] + s[1] + s[2] + s[3];
}
__device__ __forceinline__ float bmax(float v, float* s){
  v = wmax(v);
  __syncthreads();
  if ((threadIdx.x & 63) == 0) s[threadIdx.x >> 6] = v;
  __syncthreads();
  return fmaxf(fmaxf(s[0], s[1]), fmaxf(s[2], s[3]));
}

// ---------------- embedding gather (f32 h + bf16 hb) ----------------
__global__ __launch_bounds__(256) void embed_k(const int* __restrict__ x,
    const float* __restrict__ tok, float* __restrict__ h, short* __restrict__ hb){
  int idx = blockIdx.x * 256 + threadIdx.x;
  int row = idx >> 9;
  int d   = idx & 511;
  float v = tok[x[row] * D + d];
  h[idx]  = v;
  hb[idx] = f2bf(v);
}

// ---------------- bias concat: bqkv[L][1536] ----------------
__global__ __launch_bounds__(256) void bcat_k(const float* __restrict__ bq,
    const float* __restrict__ bk, const float* __restrict__ bv,
    float* __restrict__ out){
  int i = blockIdx.x * 256 + threadIdx.x;          // L*1536 = 7680
  if (i >= NL * 1536) return;
  int lay = i / 1536, c = i % 1536;
  float v = (c < 512) ? bq[lay * 512 + c]
          : (c < 1024) ? bk[lay * 512 + c - 512]
                       : bv[lay * 512 + c - 1024];
  out[i] = v;
}

// ---------------- weight transpose + bf16 cast: in[K][N] f32 -> out[N][K] bf16
// Wq/Wk/Wv land concatenated along N into Wqkv [L][1536][512]
__global__ __launch_bounds__(256) void wtrans_k(
    const float* __restrict__ Wq, const float* __restrict__ Wk,
    const float* __restrict__ Wv, const float* __restrict__ Wo,
    const float* __restrict__ W1, const float* __restrict__ W2,
    short* __restrict__ WqkvT, short* __restrict__ WoT,
    short* __restrict__ W1T, short* __restrict__ W2T)
{
  __shared__ float tl[64][65];
  int id = blockIdx.x;
  const float* src; short* dst; int K, N, tk, tn;
  if (id < 1280){
    int mat = id / 320, r = id % 320, lay = r / 64, tt = r % 64;
    tk = tt >> 3; tn = tt & 7; K = 512; N = 512;
    const float* s;
    short* d;
    if (mat == 0){ s = Wq; d = WqkvT + (size_t)lay * 786432; }
    else if (mat == 1){ s = Wk; d = WqkvT + (size_t)lay * 786432 + 262144; }
    else if (mat == 2){ s = Wv; d = WqkvT + (size_t)lay * 786432 + 524288; }
    else { s = Wo; d = WoT + (size_t)lay * 262144; }
    src = s + (size_t)lay * 262144; dst = d;
  } else if (id < 1920){
    int r = id - 1280, lay = r / 128, tt = r % 128;
    tk = tt >> 4; tn = tt & 15; K = 512; N = 1024;
    src = W1 + (size_t)lay * 524288; dst = W1T + (size_t)lay * 524288;
  } else {
    int r = id - 1920, lay = r / 128, tt = r % 128;
    tk = tt >> 3; tn = tt & 7; K = 1024; N = 512;
    src = W2 + (size_t)lay * 524288; dst = W2T + (size_t)lay * 524288;
  }
  const int k0 = tk * 64, n0 = tn * 64;
  const int t = threadIdx.x;
  const int lr = t >> 4, lc = (t & 15) * 4;
  #pragma unroll
  for (int s = 0; s < 4; s++){
    int row = lr + s * 16;
    float4 v = *(const float4*)&src[(size_t)(k0 + row) * N + n0 + lc];
    tl[row][lc + 0] = v.x; tl[row][lc + 1] = v.y;
    tl[row][lc + 2] = v.z; tl[row][lc + 3] = v.w;
  }
  __syncthreads();
  const int nr8 = t >> 3, kc8 = (t & 7) * 8;
  #pragma unroll
  for (int s = 0; s < 2; s++){
    int nr = nr8 + s * 32;
    bf16x8 o;
    #pragma unroll
    for (int e = 0; e < 8; e++) o[e] = f2bf(tl[kc8 + e][nr]);
    *(bf16x8*)&dst[(size_t)(n0 + nr) * K + k0 + kc8] = o;
  }
}

// ---------------- bf16 batched transpose: in[b][S][ld] -> out[b][D][S] ----------------
__global__ __launch_bounds__(256) void vtrans_k(const short* __restrict__ in, int ldIn,
                                                short* __restrict__ out){
  __shared__ short tl[64][72];
  const int b = blockIdx.z;
  const int j0 = blockIdx.y * 64, d0 = blockIdx.x * 64;
  in  += (size_t)b * S * ldIn;
  out += (size_t)b * D * S;
  const int t = threadIdx.x;
  const int r = t >> 3, c8 = (t & 7) * 8;
  #pragma unroll
  for (int s = 0; s < 2; s++){
    int row = r + s * 32;
    *(bf16x8*)&tl[row][c8] = *(const bf16x8*)&in[(size_t)(j0 + row) * ldIn + d0 + c8];
  }
  __syncthreads();
  #pragma unroll
  for (int s = 0; s < 2; s++){
    int dr = r + s * 32;
    bf16x8 o;
    #pragma unroll
    for (int e = 0; e < 8; e++) o[e] = tl[c8 + e][dr];
    *(bf16x8*)&out[(size_t)(d0 + dr) * S + j0 + c8] = o;
  }
}

// ---------------- generic MFMA NT GEMM, BMxBN tile, BK=32, 2-phase dbuf ----------------
// MODE: 1 bf16+bias, 2 bf16+bias+relu, 3 scores epilogue (f32), 4 PV (bf16, kmax)
template<int BM, int BN, int MODE>
__global__ __launch_bounds__(256) void mm_nt(
    const short* __restrict__ A, int ldA,
    const short* __restrict__ B, int ldB,
    const float* __restrict__ bias, void* __restrict__ C, int ldC,
    const float* __restrict__ qrel,
    int K, long batA, long batB, long batC)
{
  const int b  = blockIdx.z;
  const int m0 = blockIdx.y * BM, n0 = blockIdx.x * BN;
  if (MODE == 3 && n0 > m0) return;          // tile fully above causal diagonal
  __shared__ short As[2 * BM * 32];
  __shared__ short Bs[2 * BN * 32];
  int nk = K / 32;
  if (MODE == 4){ int km = (m0 + BM) / 32; nk = km < nk ? km : nk; }

  constexpr int FM = BM / 32, FN = BN / 32;
  f32x4 acc[FM][FN];
  const f32x4 z = {0.f, 0.f, 0.f, 0.f};
  #pragma unroll
  for (int m = 0; m < FM; m++)
    #pragma unroll
    for (int n = 0; n < FN; n++) acc[m][n] = z;

  const int t = threadIdx.x, l = t & 63, w = t >> 6;
  const short* ga = A + (size_t)b * batA + ((size_t)m0 + (t >> 2)) * ldA + (t & 3) * 8;
  const short* gb = B + (size_t)b * batB + ((size_t)n0 + (t >> 2)) * ldB + (t & 3) * 8;
  char* lA = (char*)As + w * 1024;           // wave-uniform LDS base
  char* lB = (char*)Bs + w * 1024;

  // prologue: stage k-step 0 into buffer 0
  #pragma unroll
  for (int i = 0; i < BM / 64; i++) gload16(ga + (size_t)i * 64 * ldA, lA + i * 4096);
  #pragma unroll
  for (int i = 0; i < BN / 64; i++) gload16(gb + (size_t)i * 64 * ldB, lB + i * 4096);
  __syncthreads();

  const int wm = (w >> 1) * (BM / 2), wn = (w & 1) * (BN / 2);
  const int kc = (l >> 4) * 8;
  for (int ks = 0; ks < nk; ks++){
    const int cur = ks & 1;
    if (ks + 1 < nk){
      const int nxt = cur ^ 1;
      const short* ga2 = ga + (size_t)(ks + 1) * 32;
      const short* gb2 = gb + (size_t)(ks + 1) * 32;
      #pragma unroll
      for (int i = 0; i < BM / 64; i++)
        gload16(ga2 + (size_t)i * 64 * ldA, lA + nxt * (BM * 64) + i * 4096);
      #pragma unroll
      for (int i = 0; i < BN / 64; i++)
        gload16(gb2 + (size_t)i * 64 * ldB, lB + nxt * (BN * 64) + i * 4096);
    }
    const short* Ab = As + cur * (BM * 32);
    const short* Bb = Bs + cur * (BN * 32);
    bf16x8 af[FM], bfr[FN];
    #pragma unroll
    for (int m = 0; m < FM; m++)
      af[m] = *(const bf16x8*)&Ab[(wm + m * 16 + (l & 15)) * 32 + kc];
    #pragma unroll
    for (int n = 0; n < FN; n++)
      bfr[n] = *(const bf16x8*)&Bb[(wn + n * 16 + (l & 15)) * 32 + kc];
    #pragma unroll
    for (int m = 0; m < FM; m++)
      #pragma unroll
      for (int n = 0; n < FN; n++)
        acc[m][n] = __builtin_amdgcn_mfma_f32_16x16x32_bf16(af[m], bfr[n], acc[m][n], 0, 0, 0);
    __syncthreads();
  }

  const size_t cbase = (size_t)b * batC;
  #pragma unroll
  for (int m = 0; m < FM; m++){
    const int rbase = m0 + wm + m * 16 + (l >> 4) * 4;
    #pragma unroll
    for (int n = 0; n < FN; n++){
      const int col = n0 + wn + n * 16 + (l & 15);
      #pragma unroll
      for (int r = 0; r < 4; r++){
        const int row = rbase + r;
        float v = acc[m][n][r];
        if (MODE == 1 || MODE == 2) v += bias[col];
        if (MODE == 2) v = fmaxf(v, 0.f);
        if (MODE == 3){
          float sv;
          if (col <= row){
            int dd = row - col; if (dd > 10) dd = 10;
            sv = v * (1.0f / 512.0f)
               + qrel[((size_t)b * S + row) * 16 + dd] * 0.044194173824159216f;
          } else sv = -1e9f;
          ((float*)C)[cbase + (size_t)row * ldC + col] = sv;
        } else {
          ((short*)C)[cbase + (size_t)row * ldC + col] = f2bf(v);
        }
      }
    }
  }
}

// ---------------- qrel[b,i,c] = q[b,i,:] . rel_emb[c,:] (bf16 q, ld 1536) ----------------
__global__ __launch_bounds__(256) void qrel_k(
    const short* __restrict__ q, const float* __restrict__ rel,
    float* __restrict__ qr)
{
  const int w = threadIdx.x >> 6, lane = threadIdx.x & 63;
  const int row = blockIdx.x * 4 + w;
  bf16x8 q8 = *(const bf16x8*)&q[(size_t)row * 1536 + lane * 8];
  float qv[8];
  #pragma unroll
  for (int e = 0; e < 8; e++) qv[e] = bf2f(q8[e]);
  #pragma unroll
  for (int c = 0; c < 11; c++){
    const float* rp = rel + c * D + lane * 8;
    float s = 0.f;
    #pragma unroll
    for (int e = 0; e < 8; e++) s = fmaf(qv[e], rp[e], s);
    s = wsum(s);
    if (lane == 0) qr[(size_t)row * 16 + c] = s;
  }
}

// ---------------- softmax row (f32 in) -> bf16 p, zeros above diagonal ----------------
__global__ __launch_bounds__(256) void softmax_k(const float* __restrict__ sc,
                                                 short* __restrict__ p){
  __shared__ float red[4];
  const int row = blockIdx.x;
  const int i = row & (S - 1);
  const int n = i + 1;
  const float* sr = sc + (size_t)row * S;
  short* pr = p + (size_t)row * S;
  const int t = threadIdx.x;
  float a = (t < n)       ? sr[t]       : -1e30f;
  float c = (t + 256 < n) ? sr[t + 256] : -1e30f;
  float m = bmax(fmaxf(a, c), red);
  float e0 = (t < n)       ? __expf(a - m) : 0.f;
  float e1 = (t + 256 < n) ? __expf(c - m) : 0.f;
  float sum = bsum(e0 + e1, red);
  float inv = 1.0f / sum;
  pr[t]       = f2bf(e0 * inv);
  pr[t + 256] = f2bf(e1 * inv);
}

// ---------------- h = LN(h + y) (y bf16); also emit bf16 copy ----------------
__global__ __launch_bounds__(256) void add_ln_k(
    float* __restrict__ h, const short* __restrict__ y,
    const float* __restrict__ g, const float* __restrict__ be,
    short* __restrict__ hb)
{
  __shared__ float red[4];
  const int row = blockIdx.x;
  float* hr = h + (size_t)row * D;
  const short* yr = y + (size_t)row * D;
  short* hbr = hb + (size_t)row * D;
  const int t = threadIdx.x;
  float v0 = hr[t]       + bf2f(yr[t]);
  float v1 = hr[t + 256] + bf2f(yr[t + 256]);
  float mu = bsum(v0 + v1, red) * (1.0f / 512.0f);
  float d0 = v0 - mu, d1 = v1 - mu;
  float var = bsum(d0 * d0 + d1 * d1, red) * (1.0f / 512.0f);
  float rcp = rsqrtf(var + 1e-5f);
  float o0 = d0 * rcp * g[t]       + be[t];
  float o1 = d1 * rcp * g[t + 256] + be[t + 256];
  hr[t]        = o0;
  hr[t + 256]  = o1;
  hbr[t]       = f2bf(o0);
  hbr[t + 256] = f2bf(o1);
}

// ---------------- driver ----------------
extern "C" void kernel_launch(void* const* d_in, const int* in_sizes, int n_in,
                              void* d_out, int out_size, void* d_ws, size_t ws_size,
                              hipStream_t stream)
{
  const int*   x   = (const int*)  d_in[0];
  const float* tok = (const float*)d_in[1];
  const float* rel = (const float*)d_in[2];
  const float* Wq  = (const float*)d_in[3];  const float* bq = (const float*)d_in[4];
  const float* Wk  = (const float*)d_in[5];  const float* bk = (const float*)d_in[6];
  const float* Wv  = (const float*)d_in[7];  const float* bv = (const float*)d_in[8];
  const float* Wo  = (const float*)d_in[9];  const float* bo = (const float*)d_in[10];
  const float* W1  = (const float*)d_in[11]; const float* b1 = (const float*)d_in[12];
  const float* W2  = (const float*)d_in[13]; const float* b2 = (const float*)d_in[14];
  const float* g1  = (const float*)d_in[15]; const float* be1 = (const float*)d_in[16];
  const float* g2  = (const float*)d_in[17]; const float* be2 = (const float*)d_in[18];
  (void)in_sizes; (void)n_in; (void)out_size; (void)ws_size;

  float* h = (float*)d_out;                  // [8192][512] f32

  char* ws = (char*)d_ws;
  const size_t MB = 1 << 20;
  short* hb    = (short*)(ws);               // 8MB
  short* qkv   = (short*)(ws + 8 * MB);      // 24MB  [M][1536]
  short* vT    = (short*)(ws + 32 * MB);     // 8MB   [b][D][S]
  char*  slabS = ws + 40 * MB;               // 16MB  scores(f32) / ffmid(bf16)
  short* p     = (short*)(ws + 56 * MB);     // 8MB   (also ffout later)
  short* ctx   = (short*)(ws + 64 * MB);     // 8MB
  short* xatt  = (short*)(ws + 72 * MB);     // 8MB
  float* qrelb = (float*)(ws + 80 * MB);     // 512KB
  float* bqkv  = (float*)(ws + 80 * MB + 512 * 1024);  // 30KB
  short* wb    = (short*)(ws + 81 * MB);     // 20MB transposed weights
  short* WqkvT = wb;                          // 5*1536*512
  short* WoT   = WqkvT + (size_t)5 * 786432;  // 5*512*512
  short* W1T   = WoT   + (size_t)5 * 262144;  // 5*512*1024
  short* W2T   = W1T   + (size_t)5 * 524288;  // 5*1024*512

  float* scores = (float*)slabS;
  short* ffmid  = (short*)slabS;
  short* ffout  = p;

  const int M = NB * S;                      // 8192

  wtrans_k<<<2560, 256, 0, stream>>>(Wq, Wk, Wv, Wo, W1, W2, WqkvT, WoT, W1T, W2T);
  bcat_k<<<30, 256, 0, stream>>>(bq, bk, bv, bqkv);
  embed_k<<<(size_t)M * D / 256, 256, 0, stream>>>(x, tok, h, hb);

  for (int l = 0; l < NL; l++){
    // fused QKV: [8192,512] @ [512,1536] -> qkv [8192][1536]
    mm_nt<128, 128, 1><<<dim3(12, 64, 1), 256, 0, stream>>>(
        hb, 512, WqkvT + (size_t)l * 786432, 512, bqkv + l * 1536,
        qkv, 1536, nullptr, 512, 0, 0, 0);

    vtrans_k<<<dim3(8, 8, NB), 256, 0, stream>>>(qkv + 1024, 1536, vT);
    qrel_k<<<M / 4, 256, 0, stream>>>(qkv, rel, qrelb);

    mm_nt<64, 64, 3><<<dim3(8, 8, NB), 256, 0, stream>>>(
        qkv, 1536, qkv + 512, 1536, nullptr,
        scores, 512, qrelb, 512, (long)S * 1536, (long)S * 1536, (long)S * S);

    softmax_k<<<M, 256, 0, stream>>>(scores, p);

    mm_nt<128, 64, 4><<<dim3(8, 4, NB), 256, 0, stream>>>(
        p, 512, vT, 512, nullptr,
        ctx, 512, nullptr, 512, (long)S * S, (long)D * S, (long)S * D);

    mm_nt<128, 64, 1><<<dim3(8, 64, 1), 256, 0, stream>>>(
        ctx, 512, WoT + (size_t)l * 262144, 512, bo + l * 512,
        xatt, 512, nullptr, 512, 0, 0, 0);
    add_ln_k<<<M, 256, 0, stream>>>(h, xatt, g1 + l * 512, be1 + l * 512, hb);

    mm_nt<128, 128, 2><<<dim3(8, 64, 1), 256, 0, stream>>>(
        hb, 512, W1T + (size_t)l * 524288, 512, b1 + l * 1024,
        ffmid, 1024, nullptr, 512, 0, 0, 0);
    mm_nt<128, 64, 1><<<dim3(8, 64, 1), 256, 0, stream>>>(
        ffmid, 1024, W2T + (size_t)l * 524288, 1024, b2 + l * 512,
        ffout, 512, nullptr, 1024, 0, 0, 0);
    add_ln_k<<<M, 256, 0, stream>>>(h, ffout, g2 + l * 512, be2 + l * 512, hb);
  }
}

// Round 4
// 727.908 us; speedup vs baseline: 4.6245x; 1.0670x over previous
//
#include <hip/hip_runtime.h>
#include <math.h>

#define S 512
#define D 512
#define FFD 1024
#define NB 16
#define NL 5

typedef __attribute__((ext_vector_type(8))) short bf16x8;
typedef __attribute__((ext_vector_type(4))) float f32x4;

// ---------------- bf16 helpers ----------------
__device__ __forceinline__ short f2bf(float f){
  union { float f; unsigned u; } c; c.f = f;
  unsigned r = c.u + 0x7FFFu + ((c.u >> 16) & 1u);   // RNE
  return (short)(r >> 16);
}
__device__ __forceinline__ float bf2f(short s){
  union { unsigned u; float f; } c; c.u = ((unsigned)(unsigned short)s) << 16;
  return c.f;
}

// async global->LDS, 16B per lane; lds ptr must be wave-uniform base
__device__ __forceinline__ void gload16(const void* g, void* l){
  __builtin_amdgcn_global_load_lds(
      (const __attribute__((address_space(1))) void*)g,
      (__attribute__((address_space(3))) void*)l, 16, 0, 0);
}

// ---------------- reduction helpers ----------------
__device__ __forceinline__ float wsum(float v){
  #pragma unroll
  for (int o = 32; o; o >>= 1) v += __shfl_down(v, o, 64);
  return v;
}
__device__ __forceinline__ float wmax(float v){
  #pragma unroll
  for (int o = 32; o; o >>= 1) v = fmaxf(v, __shfl_down(v, o, 64));
  return v;
}
__device__ __forceinline__ float bsum(float v, float* s){
  v = wsum(v);
  __syncthreads();
  if ((threadIdx.x & 63) == 0) s[threadIdx.x >> 6] = v;
  __syncthreads();
  return s[0] + s[1] + s[2] + s[3];
}
__device__ __forceinline__ float bmax(float v, float* s){
  v = wmax(v);
  __syncthreads();
  if ((threadIdx.x & 63) == 0) s[threadIdx.x >> 6] = v;
  __syncthreads();
  return fmaxf(fmaxf(s[0], s[1]), fmaxf(s[2], s[3]));
}

// ---------------- embedding gather (f32 h + bf16 hb) ----------------
__global__ __launch_bounds__(256) void embed_k(const int* __restrict__ x,
    const float* __restrict__ tok, float* __restrict__ h, short* __restrict__ hb){
  int idx = blockIdx.x * 256 + threadIdx.x;
  int row = idx >> 9;
  int d   = idx & 511;
  float v = tok[x[row] * D + d];
  h[idx]  = v;
  hb[idx] = f2bf(v);
}

// ---------------- bias concat: bqkv[L][1536] ----------------
__global__ __launch_bounds__(256) void bcat_k(const float* __restrict__ bq,
    const float* __restrict__ bk, const float* __restrict__ bv,
    float* __restrict__ out){
  int i = blockIdx.x * 256 + threadIdx.x;          // L*1536 = 7680
  if (i >= NL * 1536) return;
  int lay = i / 1536, c = i % 1536;
  float v = (c < 512) ? bq[lay * 512 + c]
          : (c < 1024) ? bk[lay * 512 + c - 512]
                       : bv[lay * 512 + c - 1024];
  out[i] = v;
}

// ---------------- weight transpose + bf16 cast: in[K][N] f32 -> out[N][K] bf16
__global__ __launch_bounds__(256) void wtrans_k(
    const float* __restrict__ Wq, const float* __restrict__ Wk,
    const float* __restrict__ Wv, const float* __restrict__ Wo,
    const float* __restrict__ W1, const float* __restrict__ W2,
    short* __restrict__ WqkvT, short* __restrict__ WoT,
    short* __restrict__ W1T, short* __restrict__ W2T)
{
  __shared__ float tl[64][65];
  int id = blockIdx.x;
  const float* src; short* dst; int K, N, tk, tn;
  if (id < 1280){
    int mat = id / 320, r = id % 320, lay = r / 64, tt = r % 64;
    tk = tt >> 3; tn = tt & 7; K = 512; N = 512;
    const float* s;
    short* d;
    if (mat == 0){ s = Wq; d = WqkvT + (size_t)lay * 786432; }
    else if (mat == 1){ s = Wk; d = WqkvT + (size_t)lay * 786432 + 262144; }
    else if (mat == 2){ s = Wv; d = WqkvT + (size_t)lay * 786432 + 524288; }
    else { s = Wo; d = WoT + (size_t)lay * 262144; }
    src = s + (size_t)lay * 262144; dst = d;
  } else if (id < 1920){
    int r = id - 1280, lay = r / 128, tt = r % 128;
    tk = tt >> 4; tn = tt & 15; K = 512; N = 1024;
    src = W1 + (size_t)lay * 524288; dst = W1T + (size_t)lay * 524288;
  } else {
    int r = id - 1920, lay = r / 128, tt = r % 128;
    tk = tt >> 3; tn = tt & 7; K = 1024; N = 512;
    src = W2 + (size_t)lay * 524288; dst = W2T + (size_t)lay * 524288;
  }
  const int k0 = tk * 64, n0 = tn * 64;
  const int t = threadIdx.x;
  const int lr = t >> 4, lc = (t & 15) * 4;
  #pragma unroll
  for (int s = 0; s < 4; s++){
    int row = lr + s * 16;
    float4 v = *(const float4*)&src[(size_t)(k0 + row) * N + n0 + lc];
    tl[row][lc + 0] = v.x; tl[row][lc + 1] = v.y;
    tl[row][lc + 2] = v.z; tl[row][lc + 3] = v.w;
  }
  __syncthreads();
  const int nr8 = t >> 3, kc8 = (t & 7) * 8;
  #pragma unroll
  for (int s = 0; s < 2; s++){
    int nr = nr8 + s * 32;
    bf16x8 o;
    #pragma unroll
    for (int e = 0; e < 8; e++) o[e] = f2bf(tl[kc8 + e][nr]);
    *(bf16x8*)&dst[(size_t)(n0 + nr) * K + k0 + kc8] = o;
  }
}

// ---------------- staging: ROWS x (PAN*32) bf16 tile, panel-major LDS ----------------
// LDS layout: [panel][row][32], each 1KB call = 16 rows of one panel.
template<int ROWS, int PAN>
__device__ __forceinline__ void stage_tile(const short* __restrict__ G, int ld,
                                           int kbase, char* ldsBase, int w, int l){
  constexpr int CALLS = ROWS * PAN / 64;   // per-wave gload16 calls
  #pragma unroll
  for (int c = 0; c < CALLS; c++){
    const int idx = w * CALLS + c;
    const int panel = idx / (ROWS / 16);
    const int chunk = idx % (ROWS / 16);
    const short* src = G + (size_t)(chunk * 16 + (l >> 2)) * ld
                         + kbase + panel * 32 + (l & 3) * 8;
    gload16(src, ldsBase + idx * 1024);
  }
}

// ---------------- generic MFMA NT GEMM, BMxBN tile, BK in {32,64}, 2-phase dbuf ----
// MODE: 1 bf16+bias, 2 bf16+bias+relu, 3 scores->bf16, 4 PV bf16 (kmax), 5 QKV(+vT)
template<int BM, int BN, int MODE, int BK>
__global__ __launch_bounds__(256) void mm_nt(
    const short* __restrict__ A, int ldA,
    const short* __restrict__ B, int ldB,
    const float* __restrict__ bias, void* __restrict__ C, int ldC,
    const float* __restrict__ qrel, short* __restrict__ vT,
    int K, long batA, long batB, long batC)
{
  constexpr int PAN = BK / 32;
  const int b  = blockIdx.z;
  const int m0 = blockIdx.y * BM, n0 = blockIdx.x * BN;
  if (MODE == 3 && n0 > m0) return;          // tile fully above causal diagonal
  __shared__ short As[2 * BM * BK];
  __shared__ short Bs[2 * BN * BK];
  int nk = K / BK;
  if (MODE == 4){ int km = (m0 + BM) / BK; nk = km < nk ? km : nk; }

  constexpr int FM = BM / 32, FN = BN / 32;
  f32x4 acc[FM][FN];
  const f32x4 z = {0.f, 0.f, 0.f, 0.f};
  #pragma unroll
  for (int m = 0; m < FM; m++)
    #pragma unroll
    for (int n = 0; n < FN; n++) acc[m][n] = z;

  const int t = threadIdx.x, l = t & 63, w = t >> 6;
  const short* Ag = A + (size_t)b * batA + (size_t)m0 * ldA;
  const short* Bg = B + (size_t)b * batB + (size_t)n0 * ldB;

  // prologue: stage k-step 0 into buffer 0
  stage_tile<BM, PAN>(Ag, ldA, 0, (char*)As, w, l);
  stage_tile<BN, PAN>(Bg, ldB, 0, (char*)Bs, w, l);
  __syncthreads();

  const int wm = (w >> 1) * (BM / 2), wn = (w & 1) * (BN / 2);
  const int kc = (l >> 4) * 8;
  for (int ks = 0; ks < nk; ks++){
    const int cur = ks & 1;
    if (ks + 1 < nk){
      const int nxt = cur ^ 1;
      stage_tile<BM, PAN>(Ag, ldA, (ks + 1) * BK, (char*)As + nxt * (BM * BK * 2), w, l);
      stage_tile<BN, PAN>(Bg, ldB, (ks + 1) * BK, (char*)Bs + nxt * (BN * BK * 2), w, l);
    }
    const short* Ab = As + cur * (BM * BK);
    const short* Bb = Bs + cur * (BN * BK);
    #pragma unroll
    for (int p = 0; p < PAN; p++){
      bf16x8 af[FM], bfr[FN];
      #pragma unroll
      for (int m = 0; m < FM; m++)
        af[m] = *(const bf16x8*)&Ab[p * BM * 32 + (wm + m * 16 + (l & 15)) * 32 + kc];
      #pragma unroll
      for (int n = 0; n < FN; n++)
        bfr[n] = *(const bf16x8*)&Bb[p * BN * 32 + (wn + n * 16 + (l & 15)) * 32 + kc];
      #pragma unroll
      for (int m = 0; m < FM; m++)
        #pragma unroll
        for (int n = 0; n < FN; n++)
          acc[m][n] = __builtin_amdgcn_mfma_f32_16x16x32_bf16(af[m], bfr[n], acc[m][n], 0, 0, 0);
    }
    __syncthreads();
  }

  const size_t cbase = (size_t)b * batC;
  #pragma unroll
  for (int m = 0; m < FM; m++){
    const int rbase = m0 + wm + m * 16 + (l >> 4) * 4;
    #pragma unroll
    for (int n = 0; n < FN; n++){
      const int col = n0 + wn + n * 16 + (l & 15);
      if (MODE == 5 && col >= 1024){
        // write V^T directly: vT[b][d][s], 4 consecutive s per lane -> 8B store
        const int d = col - 1024;
        const int bb = rbase >> 9, s0 = rbase & 511;
        union { short s[4]; uint2 u; } tmp;
        #pragma unroll
        for (int r = 0; r < 4; r++) tmp.s[r] = f2bf(acc[m][n][r] + bias[col]);
        *(uint2*)&vT[(size_t)bb * 262144 + (size_t)d * 512 + s0] = tmp.u;
        continue;
      }
      #pragma unroll
      for (int r = 0; r < 4; r++){
        const int row = rbase + r;
        float v = acc[m][n][r];
        if (MODE == 1 || MODE == 2 || MODE == 5) v += bias[col];
        if (MODE == 2) v = fmaxf(v, 0.f);
        if (MODE == 3){
          float sv;
          if (col <= row){
            int dd = row - col; if (dd > 10) dd = 10;
            sv = v * (1.0f / 512.0f)
               + qrel[((size_t)b * S + row) * 16 + dd] * 0.044194173824159216f;
          } else sv = -1e9f;
          ((short*)C)[cbase + (size_t)row * ldC + col] = f2bf(sv);
        } else {
          ((short*)C)[cbase + (size_t)row * ldC + col] = f2bf(v);
        }
      }
    }
  }
}

// ---------------- qrel[b,i,c] = q[b,i,:] . rel_emb[c,:] (bf16 q, ld 1024) ----------
__global__ __launch_bounds__(256) void qrel_k(
    const short* __restrict__ q, const float* __restrict__ rel,
    float* __restrict__ qr)
{
  const int w = threadIdx.x >> 6, lane = threadIdx.x & 63;
  const int row = blockIdx.x * 4 + w;
  bf16x8 q8 = *(const bf16x8*)&q[(size_t)row * 1024 + lane * 8];
  float qv[8];
  #pragma unroll
  for (int e = 0; e < 8; e++) qv[e] = bf2f(q8[e]);
  #pragma unroll
  for (int c = 0; c < 11; c++){
    const float* rp = rel + c * D + lane * 8;
    float s = 0.f;
    #pragma unroll
    for (int e = 0; e < 8; e++) s = fmaf(qv[e], rp[e], s);
    s = wsum(s);
    if (lane == 0) qr[(size_t)row * 16 + c] = s;
  }
}

// ---------------- softmax row (bf16 in) -> bf16 p, zeros above diagonal ----------
__global__ __launch_bounds__(256) void softmax_k(const short* __restrict__ sc,
                                                 short* __restrict__ p){
  __shared__ float red[4];
  const int row = blockIdx.x;
  const int i = row & (S - 1);
  const int n = i + 1;
  const short* sr = sc + (size_t)row * S;
  short* pr = p + (size_t)row * S;
  const int t = threadIdx.x;
  const int c0 = t * 2;
  unsigned v = *(const unsigned*)&sr[c0];
  float a = bf2f((short)(v & 0xFFFF));
  float c = bf2f((short)(v >> 16));
  a = (c0 < n)     ? a : -1e30f;
  c = (c0 + 1 < n) ? c : -1e30f;
  float m = bmax(fmaxf(a, c), red);
  float e0 = (c0 < n)     ? __expf(a - m) : 0.f;
  float e1 = (c0 + 1 < n) ? __expf(c - m) : 0.f;
  float sum = bsum(e0 + e1, red);
  float inv = 1.0f / sum;
  unsigned o = (unsigned)(unsigned short)f2bf(e0 * inv)
             | ((unsigned)(unsigned short)f2bf(e1 * inv) << 16);
  *(unsigned*)&pr[c0] = o;
}

// ---------------- h = LN(h + y) (y bf16); also emit bf16 copy ----------------
__global__ __launch_bounds__(256) void add_ln_k(
    float* __restrict__ h, const short* __restrict__ y,
    const float* __restrict__ g, const float* __restrict__ be,
    short* __restrict__ hb)
{
  __shared__ float red[4];
  const int row = blockIdx.x;
  float* hr = h + (size_t)row * D;
  const short* yr = y + (size_t)row * D;
  short* hbr = hb + (size_t)row * D;
  const int t = threadIdx.x;
  float v0 = hr[t]       + bf2f(yr[t]);
  float v1 = hr[t + 256] + bf2f(yr[t + 256]);
  float mu = bsum(v0 + v1, red) * (1.0f / 512.0f);
  float d0 = v0 - mu, d1 = v1 - mu;
  float var = bsum(d0 * d0 + d1 * d1, red) * (1.0f / 512.0f);
  float rcp = rsqrtf(var + 1e-5f);
  float o0 = d0 * rcp * g[t]       + be[t];
  float o1 = d1 * rcp * g[t + 256] + be[t + 256];
  hr[t]        = o0;
  hr[t + 256]  = o1;
  hbr[t]       = f2bf(o0);
  hbr[t + 256] = f2bf(o1);
}

// ---------------- driver ----------------
extern "C" void kernel_launch(void* const* d_in, const int* in_sizes, int n_in,
                              void* d_out, int out_size, void* d_ws, size_t ws_size,
                              hipStream_t stream)
{
  const int*   x   = (const int*)  d_in[0];
  const float* tok = (const float*)d_in[1];
  const float* rel = (const float*)d_in[2];
  const float* Wq  = (const float*)d_in[3];  const float* bq = (const float*)d_in[4];
  const float* Wk  = (const float*)d_in[5];  const float* bk = (const float*)d_in[6];
  const float* Wv  = (const float*)d_in[7];  const float* bv = (const float*)d_in[8];
  const float* Wo  = (const float*)d_in[9];  const float* bo = (const float*)d_in[10];
  const float* W1  = (const float*)d_in[11]; const float* b1 = (const float*)d_in[12];
  const float* W2  = (const float*)d_in[13]; const float* b2 = (const float*)d_in[14];
  const float* g1  = (const float*)d_in[15]; const float* be1 = (const float*)d_in[16];
  const float* g2  = (const float*)d_in[17]; const float* be2 = (const float*)d_in[18];
  (void)in_sizes; (void)n_in; (void)out_size; (void)ws_size;

  float* h = (float*)d_out;                  // [8192][512] f32

  char* ws = (char*)d_ws;
  const size_t MB = 1 << 20;
  short* hb     = (short*)(ws);              // 8MB
  short* qkv    = (short*)(ws + 8 * MB);     // 16MB [M][1024] (q|k)
  short* vT     = (short*)(ws + 24 * MB);    // 8MB  [b][D][S]
  short* scores = (short*)(ws + 32 * MB);    // 8MB  bf16
  short* p      = (short*)(ws + 40 * MB);    // 8MB  bf16
  short* ffmid  = (short*)(ws + 32 * MB);    // 16MB spans scores+p (dead by FFN1)
  short* ctx    = (short*)(ws + 48 * MB);    // 8MB  (also ffout)
  short* xatt   = (short*)(ws + 56 * MB);    // 8MB
  float* qrelb  = (float*)(ws + 64 * MB);    // 512KB
  float* bqkv   = (float*)(ws + 64 * MB + 512 * 1024);
  short* wb     = (short*)(ws + 65 * MB);    // 20MB transposed weights
  short* WqkvT  = wb;
  short* WoT    = WqkvT + (size_t)5 * 786432;
  short* W1T    = WoT   + (size_t)5 * 262144;
  short* W2T    = W1T   + (size_t)5 * 524288;
  short* ffout  = ctx;

  const int M = NB * S;                      // 8192

  wtrans_k<<<2560, 256, 0, stream>>>(Wq, Wk, Wv, Wo, W1, W2, WqkvT, WoT, W1T, W2T);
  bcat_k<<<30, 256, 0, stream>>>(bq, bk, bv, bqkv);
  embed_k<<<(size_t)M * D / 256, 256, 0, stream>>>(x, tok, h, hb);

  for (int l = 0; l < NL; l++){
    // fused QKV: q,k -> qkv[M][1024]; v -> vT[b][D][S] directly
    mm_nt<128, 128, 5, 32><<<dim3(12, 64, 1), 256, 0, stream>>>(
        hb, 512, WqkvT + (size_t)l * 786432, 512, bqkv + l * 1536,
        qkv, 1024, nullptr, vT, 512, 0, 0, 0);

    qrel_k<<<M / 4, 256, 0, stream>>>(qkv, rel, qrelb);

    mm_nt<64, 64, 3, 64><<<dim3(8, 8, NB), 256, 0, stream>>>(
        qkv, 1024, qkv + 512, 1024, nullptr,
        scores, 512, qrelb, nullptr, 512,
        (long)S * 1024, (long)S * 1024, (long)S * S);

    softmax_k<<<M, 256, 0, stream>>>(scores, p);

    mm_nt<128, 64, 4, 64><<<dim3(8, 4, NB), 256, 0, stream>>>(
        p, 512, vT, 512, nullptr,
        ctx, 512, nullptr, nullptr, 512,
        (long)S * S, (long)D * S, (long)S * D);

    mm_nt<128, 64, 1, 64><<<dim3(8, 64, 1), 256, 0, stream>>>(
        ctx, 512, WoT + (size_t)l * 262144, 512, bo + l * 512,
        xatt, 512, nullptr, nullptr, 512, 0, 0, 0);
    add_ln_k<<<M, 256, 0, stream>>>(h, xatt, g1 + l * 512, be1 + l * 512, hb);

    mm_nt<128, 128, 2, 32><<<dim3(8, 64, 1), 256, 0, stream>>>(
        hb, 512, W1T + (size_t)l * 524288, 512, b1 + l * 1024,
        ffmid, 1024, nullptr, nullptr, 512, 0, 0, 0);
    mm_nt<128, 64, 1, 64><<<dim3(8, 64, 1), 256, 0, stream>>>(
        ffmid, 1024, W2T + (size_t)l * 524288, 1024, b2 + l * 512,
        ffout, 512, nullptr, nullptr, 1024, 0, 0, 0);
    add_ln_k<<<M, 256, 0, stream>>>(h, ffout, g2 + l * 512, be2 + l * 512, hb);
  }
}

// Round 5
// 710.487 us; speedup vs baseline: 4.7379x; 1.0245x over previous
//
#include <hip/hip_runtime.h>
#include <math.h>

#define S 512
#define D 512
#define FFD 1024
#define NB 16
#define NL 5

typedef __attribute__((ext_vector_type(8))) short bf16x8;
typedef __attribute__((ext_vector_type(4))) float f32x4;

// ---------------- bf16 helpers ----------------
__device__ __forceinline__ short f2bf(float f){
  union { float f; unsigned u; } c; c.f = f;
  unsigned r = c.u + 0x7FFFu + ((c.u >> 16) & 1u);   // RNE
  return (short)(r >> 16);
}
__device__ __forceinline__ float bf2f(short s){
  union { unsigned u; float f; } c; c.u = ((unsigned)(unsigned short)s) << 16;
  return c.f;
}

// async global->LDS, 16B per lane; lds ptr must be wave-uniform base
__device__ __forceinline__ void gload16(const void* g, void* l){
  __builtin_amdgcn_global_load_lds(
      (const __attribute__((address_space(1))) void*)g,
      (__attribute__((address_space(3))) void*)l, 16, 0, 0);
}

// ---------------- reduction helpers ----------------
__device__ __forceinline__ float wsum(float v){
  #pragma unroll
  for (int o = 32; o; o >>= 1) v += __shfl_down(v, o, 64);
  return v;
}
__device__ __forceinline__ float bsum(float v, float* s){
  v = wsum(v);
  __syncthreads();
  if ((threadIdx.x & 63) == 0) s[threadIdx.x >> 6] = v;
  __syncthreads();
  return s[0] + s[1] + s[2] + s[3];
}

// ---------------- embedding gather (bf16 hb only) ----------------
__global__ __launch_bounds__(256) void embed_k(const int* __restrict__ x,
    const float* __restrict__ tok, short* __restrict__ hb){
  int idx = blockIdx.x * 256 + threadIdx.x;
  int row = idx >> 9;
  int d   = idx & 511;
  hb[idx] = f2bf(tok[x[row] * D + d]);
}

// ---------------- bias concat + brel: bqkv[L][1664] ----------------
__global__ __launch_bounds__(256) void bcat_k(const float* __restrict__ bq,
    const float* __restrict__ bk, const float* __restrict__ bv,
    const float* __restrict__ rel, float* __restrict__ out){
  int i = blockIdx.x * 256 + threadIdx.x;          // L*1664
  if (i >= NL * 1664) return;
  int lay = i / 1664, c = i % 1664;
  float v;
  if      (c <  512) v = bq[lay * 512 + c];
  else if (c < 1024) v = bk[lay * 512 + c - 512];
  else if (c < 1536) v = bv[lay * 512 + c - 1024];
  else if (c < 1547){
    int cc = c - 1536;
    float s = 0.f;
    for (int j = 0; j < 512; j++) s += bq[lay * 512 + j] * rel[cc * 512 + j];
    v = s;
  } else v = 0.f;
  out[i] = v;
}

// ---------------- Wrel: rows 1536..1551 of WqkvT: WrelT[c][k] = Wq[k]·rel[c] ----
__global__ __launch_bounds__(256) void wrel_k(
    const float* __restrict__ Wq, const float* __restrict__ rel,
    short* __restrict__ WqkvT){
  const int bid = blockIdx.x;                      // 5 * 128
  const int lay = bid >> 7, kc = bid & 127;
  const int w = threadIdx.x >> 6, lane = threadIdx.x & 63;
  const int k = kc * 4 + w;
  const float* wrow = Wq + (size_t)lay * 262144 + (size_t)k * 512 + lane * 8;
  float qv[8];
  #pragma unroll
  for (int e = 0; e < 8; e++) qv[e] = wrow[e];
  short* dst = WqkvT + (size_t)lay * 851968;
  #pragma unroll
  for (int c = 0; c < 11; c++){
    const float* rp = rel + c * 512 + lane * 8;
    float s = 0.f;
    #pragma unroll
    for (int e = 0; e < 8; e++) s = fmaf(qv[e], rp[e], s);
    s = wsum(s);
    if (lane == 0) dst[(size_t)(1536 + c) * 512 + k] = f2bf(s);
  }
  if (lane == 0){
    #pragma unroll
    for (int c = 11; c < 16; c++) dst[(size_t)(1536 + c) * 512 + k] = 0;
  }
}

// ---------------- weight transpose + bf16 cast: in[K][N] f32 -> out[N][K] bf16
__global__ __launch_bounds__(256) void wtrans_k(
    const float* __restrict__ Wq, const float* __restrict__ Wk,
    const float* __restrict__ Wv, const float* __restrict__ Wo,
    const float* __restrict__ W1, const float* __restrict__ W2,
    short* __restrict__ WqkvT, short* __restrict__ WoT,
    short* __restrict__ W1T, short* __restrict__ W2T)
{
  __shared__ float tl[64][65];
  int id = blockIdx.x;
  const float* src; short* dst; int K, N, tk, tn;
  if (id < 1280){
    int mat = id / 320, r = id % 320, lay = r / 64, tt = r % 64;
    tk = tt >> 3; tn = tt & 7; K = 512; N = 512;
    const float* s;
    short* d;
    if (mat == 0){ s = Wq; d = WqkvT + (size_t)lay * 851968; }
    else if (mat == 1){ s = Wk; d = WqkvT + (size_t)lay * 851968 + 262144; }
    else if (mat == 2){ s = Wv; d = WqkvT + (size_t)lay * 851968 + 524288; }
    else { s = Wo; d = WoT + (size_t)lay * 262144; }
    src = s + (size_t)lay * 262144; dst = d;
  } else if (id < 1920){
    int r = id - 1280, lay = r / 128, tt = r % 128;
    tk = tt >> 4; tn = tt & 15; K = 512; N = 1024;
    src = W1 + (size_t)lay * 524288; dst = W1T + (size_t)lay * 524288;
  } else {
    int r = id - 1920, lay = r / 128, tt = r % 128;
    tk = tt >> 3; tn = tt & 7; K = 1024; N = 512;
    src = W2 + (size_t)lay * 524288; dst = W2T + (size_t)lay * 524288;
  }
  const int k0 = tk * 64, n0 = tn * 64;
  const int t = threadIdx.x;
  const int lr = t >> 4, lc = (t & 15) * 4;
  #pragma unroll
  for (int s = 0; s < 4; s++){
    int row = lr + s * 16;
    float4 v = *(const float4*)&src[(size_t)(k0 + row) * N + n0 + lc];
    tl[row][lc + 0] = v.x; tl[row][lc + 1] = v.y;
    tl[row][lc + 2] = v.z; tl[row][lc + 3] = v.w;
  }
  __syncthreads();
  const int nr8 = t >> 3, kc8 = (t & 7) * 8;
  #pragma unroll
  for (int s = 0; s < 2; s++){
    int nr = nr8 + s * 32;
    bf16x8 o;
    #pragma unroll
    for (int e = 0; e < 8; e++) o[e] = f2bf(tl[kc8 + e][nr]);
    *(bf16x8*)&dst[(size_t)(n0 + nr) * K + k0 + kc8] = o;
  }
}

// ---------------- staging: ROWS x (PAN*32) bf16 tile, panel-major LDS ----------------
template<int ROWS, int PAN>
__device__ __forceinline__ void stage_tile(const short* __restrict__ G, int ld,
                                           int kbase, char* ldsBase, int w, int l){
  constexpr int CALLS = ROWS * PAN / 64;   // per-wave gload16 calls
  #pragma unroll
  for (int c = 0; c < CALLS; c++){
    const int idx = w * CALLS + c;
    const int panel = idx / (ROWS / 16);
    const int chunk = idx % (ROWS / 16);
    const short* src = G + (size_t)(chunk * 16 + (l >> 2)) * ld
                         + kbase + panel * 32 + (l & 3) * 8;
    gload16(src, ldsBase + idx * 1024);
  }
}

// ---------------- generic MFMA NT GEMM, BMxBN tile, BK in {32,64}, 2-phase dbuf ----
// MODE: 1 bf16+bias, 2 bf16+bias+relu, 3 scores->exp->bf16 p, 4 PV+normalize,
//       5 QKV fused (qkv | vT | qrel)
template<int BM, int BN, int MODE, int BK>
__global__ __launch_bounds__(256) void mm_nt(
    const short* __restrict__ A, int ldA,
    const short* __restrict__ B, int ldB,
    const float* __restrict__ bias, void* __restrict__ C, int ldC,
    const float* __restrict__ qrel, short* __restrict__ vT,
    float* __restrict__ qrelOut,
    int K, long batA, long batB, long batC)
{
  constexpr int PAN = BK / 32;
  const int b  = blockIdx.z;
  const int m0 = blockIdx.y * BM, n0 = blockIdx.x * BN;
  if (MODE == 3 && n0 > m0) return;          // tile fully above causal diagonal
  __shared__ short As[2 * BM * BK];
  __shared__ short Bs[2 * BN * BK];
  int nk = K / BK;
  if (MODE == 4){ int km = (m0 + BM) / BK; nk = km < nk ? km : nk; }

  constexpr int FM = BM / 32, FN = BN / 32;
  f32x4 acc[FM][FN];
  const f32x4 z = {0.f, 0.f, 0.f, 0.f};
  #pragma unroll
  for (int m = 0; m < FM; m++)
    #pragma unroll
    for (int n = 0; n < FN; n++) acc[m][n] = z;

  const int t = threadIdx.x, l = t & 63, w = t >> 6;
  const short* Ag = A + (size_t)b * batA + (size_t)m0 * ldA;
  const short* Bg = B + (size_t)b * batB + (size_t)n0 * ldB;

  stage_tile<BM, PAN>(Ag, ldA, 0, (char*)As, w, l);
  stage_tile<BN, PAN>(Bg, ldB, 0, (char*)Bs, w, l);
  __syncthreads();

  const int wm = (w >> 1) * (BM / 2), wn = (w & 1) * (BN / 2);
  const int kc = (l >> 4) * 8;
  float rs[FM];
  #pragma unroll
  for (int m = 0; m < FM; m++) rs[m] = 0.f;

  for (int ks = 0; ks < nk; ks++){
    const int cur = ks & 1;
    if (ks + 1 < nk){
      const int nxt = cur ^ 1;
      stage_tile<BM, PAN>(Ag, ldA, (ks + 1) * BK, (char*)As + nxt * (BM * BK * 2), w, l);
      stage_tile<BN, PAN>(Bg, ldB, (ks + 1) * BK, (char*)Bs + nxt * (BN * BK * 2), w, l);
    }
    const short* Ab = As + cur * (BM * BK);
    const short* Bb = Bs + cur * (BN * BK);
    #pragma unroll
    for (int p = 0; p < PAN; p++){
      bf16x8 af[FM], bfr[FN];
      #pragma unroll
      for (int m = 0; m < FM; m++)
        af[m] = *(const bf16x8*)&Ab[p * BM * 32 + (wm + m * 16 + (l & 15)) * 32 + kc];
      #pragma unroll
      for (int n = 0; n < FN; n++)
        bfr[n] = *(const bf16x8*)&Bb[p * BN * 32 + (wn + n * 16 + (l & 15)) * 32 + kc];
      if (MODE == 4){
        #pragma unroll
        for (int m = 0; m < FM; m++){
          float s = 0.f;
          #pragma unroll
          for (int e = 0; e < 8; e++) s += bf2f(af[m][e]);
          rs[m] += s;
        }
      }
      #pragma unroll
      for (int m = 0; m < FM; m++)
        #pragma unroll
        for (int n = 0; n < FN; n++)
          acc[m][n] = __builtin_amdgcn_mfma_f32_16x16x32_bf16(af[m], bfr[n], acc[m][n], 0, 0, 0);
    }
    __syncthreads();
  }

  float invr[FM][4];
  if (MODE == 4){
    #pragma unroll
    for (int m = 0; m < FM; m++){
      float r = rs[m];
      r += __shfl_xor(r, 16, 64);
      r += __shfl_xor(r, 32, 64);
      #pragma unroll
      for (int rr = 0; rr < 4; rr++)
        invr[m][rr] = 1.0f / __shfl(r, (l >> 4) * 4 + rr, 64);
    }
  }

  const size_t cbase = (size_t)b * batC;
  #pragma unroll
  for (int m = 0; m < FM; m++){
    const int rbase = m0 + wm + m * 16 + (l >> 4) * 4;
    #pragma unroll
    for (int n = 0; n < FN; n++){
      const int col = n0 + wn + n * 16 + (l & 15);
      if (MODE == 5 && col >= 1024 && col < 1536){
        // write V^T directly: vT[b][d][s], 4 consecutive s per lane -> 8B store
        const int d = col - 1024;
        const int bb = rbase >> 9, s0 = rbase & 511;
        union { short s[4]; uint2 u; } tmp;
        #pragma unroll
        for (int r = 0; r < 4; r++) tmp.s[r] = f2bf(acc[m][n][r] + bias[col]);
        *(uint2*)&vT[(size_t)bb * 262144 + (size_t)d * 512 + s0] = tmp.u;
        continue;
      }
      if (MODE == 5 && col >= 1536){
        if (col < 1552){
          const int c = col - 1536;
          #pragma unroll
          for (int r = 0; r < 4; r++)
            qrelOut[(size_t)(rbase + r) * 16 + c] = acc[m][n][r] + bias[col];
        }
        continue;
      }
      #pragma unroll
      for (int r = 0; r < 4; r++){
        const int row = rbase + r;
        float v = acc[m][n][r];
        if (MODE == 1 || MODE == 2 || MODE == 5) v += bias[col];
        if (MODE == 2) v = fmaxf(v, 0.f);
        if (MODE == 3){
          float e;
          if (col <= row){
            int dd = row - col; if (dd > 10) dd = 10;
            float sv = v * (1.0f / 512.0f)
                     + qrel[((size_t)b * S + row) * 16 + dd] * 0.044194173824159216f;
            e = __expf(sv);
          } else e = 0.f;
          ((short*)C)[cbase + (size_t)row * ldC + col] = f2bf(e);
        } else if (MODE == 4){
          ((short*)C)[cbase + (size_t)row * ldC + col] = f2bf(v * invr[m][r]);
        } else {
          ((short*)C)[cbase + (size_t)row * ldC + col] = f2bf(v);
        }
      }
    }
  }
}

// ---------------- h = LN(h + y), bf16 residual; FINAL writes f32 out ----------
template<int FINAL>
__global__ __launch_bounds__(256) void add_ln_k(
    short* __restrict__ hb, const short* __restrict__ y,
    const float* __restrict__ g, const float* __restrict__ be,
    float* __restrict__ hOut)
{
  __shared__ float red[4];
  const int row = blockIdx.x;
  short* hbr = hb + (size_t)row * D;
  const short* yr = y + (size_t)row * D;
  const int t = threadIdx.x;
  float v0 = bf2f(hbr[t])       + bf2f(yr[t]);
  float v1 = bf2f(hbr[t + 256]) + bf2f(yr[t + 256]);
  float mu = bsum(v0 + v1, red) * (1.0f / 512.0f);
  float d0 = v0 - mu, d1 = v1 - mu;
  float var = bsum(d0 * d0 + d1 * d1, red) * (1.0f / 512.0f);
  float rcp = rsqrtf(var + 1e-5f);
  float o0 = d0 * rcp * g[t]       + be[t];
  float o1 = d1 * rcp * g[t + 256] + be[t + 256];
  if (FINAL){
    float* ho = hOut + (size_t)row * D;
    ho[t]       = o0;
    ho[t + 256] = o1;
  } else {
    hbr[t]       = f2bf(o0);
    hbr[t + 256] = f2bf(o1);
  }
}

// ---------------- driver ----------------
extern "C" void kernel_launch(void* const* d_in, const int* in_sizes, int n_in,
                              void* d_out, int out_size, void* d_ws, size_t ws_size,
                              hipStream_t stream)
{
  const int*   x   = (const int*)  d_in[0];
  const float* tok = (const float*)d_in[1];
  const float* rel = (const float*)d_in[2];
  const float* Wq  = (const float*)d_in[3];  const float* bq = (const float*)d_in[4];
  const float* Wk  = (const float*)d_in[5];  const float* bk = (const float*)d_in[6];
  const float* Wv  = (const float*)d_in[7];  const float* bv = (const float*)d_in[8];
  const float* Wo  = (const float*)d_in[9];  const float* bo = (const float*)d_in[10];
  const float* W1  = (const float*)d_in[11]; const float* b1 = (const float*)d_in[12];
  const float* W2  = (const float*)d_in[13]; const float* b2 = (const float*)d_in[14];
  const float* g1  = (const float*)d_in[15]; const float* be1 = (const float*)d_in[16];
  const float* g2  = (const float*)d_in[17]; const float* be2 = (const float*)d_in[18];
  (void)in_sizes; (void)n_in; (void)out_size; (void)ws_size;

  float* h = (float*)d_out;                  // final f32 output only

  char* ws = (char*)d_ws;
  const size_t MB = 1 << 20;
  short* hb     = (short*)(ws);              // 8MB  bf16 residual stream
  short* qkv    = (short*)(ws + 8 * MB);     // 16MB [M][1024] (q|k)
  short* vT     = (short*)(ws + 24 * MB);    // 8MB  [b][D][S]
  short* p      = (short*)(ws + 32 * MB);    // 8MB  unnormalized exp scores
  short* ctx    = (short*)(ws + 40 * MB);    // 8MB
  short* xatt   = (short*)(ws + 48 * MB);    // 8MB (also ffout)
  short* ffmid  = (short*)(ws + 32 * MB);    // 16MB spans p+ctx (dead by FFN1)
  float* qrelb  = (float*)(ws + 56 * MB);    // 512KB [M][16] f32
  float* bqkv   = (float*)(ws + 56 * MB + 512 * 1024);  // L*1664*4 = 33KB
  short* wb     = (short*)(ws + 57 * MB);
  short* WqkvT  = wb;                                   // L*1664*512 bf16 = 8.1MB
  short* WoT    = WqkvT + (size_t)5 * 851968;           // L*512*512
  short* W1T    = WoT   + (size_t)5 * 262144;           // L*512*1024
  short* W2T    = W1T   + (size_t)5 * 524288;           // L*1024*512
  short* ffout  = xatt;

  const int M = NB * S;                      // 8192

  wtrans_k<<<2560, 256, 0, stream>>>(Wq, Wk, Wv, Wo, W1, W2, WqkvT, WoT, W1T, W2T);
  wrel_k<<<640, 256, 0, stream>>>(Wq, rel, WqkvT);
  bcat_k<<<(NL * 1664 + 255) / 256, 256, 0, stream>>>(bq, bk, bv, rel, bqkv);
  embed_k<<<(size_t)M * D / 256, 256, 0, stream>>>(x, tok, hb);

  for (int l = 0; l < NL; l++){
    // fused QKV+qrel: q,k -> qkv[M][1024]; v -> vT; qrel -> qrelb
    mm_nt<128, 128, 5, 32><<<dim3(13, 64, 1), 256, 0, stream>>>(
        hb, 512, WqkvT + (size_t)l * 851968, 512, bqkv + l * 1664,
        qkv, 1024, nullptr, vT, qrelb, 512, 0, 0, 0);

    // scores -> exp -> p (unnormalized, zeros above diagonal)
    mm_nt<64, 64, 3, 64><<<dim3(8, 8, NB), 256, 0, stream>>>(
        qkv, 1024, qkv + 512, 1024, nullptr,
        p, 512, qrelb, nullptr, nullptr, 512,
        (long)S * 1024, (long)S * 1024, (long)S * S);

    // PV + row-sum normalize
    mm_nt<64, 64, 4, 64><<<dim3(8, 8, NB), 256, 0, stream>>>(
        p, 512, vT, 512, nullptr,
        ctx, 512, nullptr, nullptr, nullptr, 512,
        (long)S * S, (long)D * S, (long)S * D);

    mm_nt<128, 64, 1, 64><<<dim3(8, 64, 1), 256, 0, stream>>>(
        ctx, 512, WoT + (size_t)l * 262144, 512, bo + l * 512,
        xatt, 512, nullptr, nullptr, nullptr, 512, 0, 0, 0);
    add_ln_k<0><<<M, 256, 0, stream>>>(hb, xatt, g1 + l * 512, be1 + l * 512, nullptr);

    mm_nt<128, 128, 2, 32><<<dim3(8, 64, 1), 256, 0, stream>>>(
        hb, 512, W1T + (size_t)l * 524288, 512, b1 + l * 1024,
        ffmid, 1024, nullptr, nullptr, nullptr, 512, 0, 0, 0);
    mm_nt<128, 64, 1, 64><<<dim3(8, 64, 1), 256, 0, stream>>>(
        ffmid, 1024, W2T + (size_t)l * 524288, 1024, b2 + l * 512,
        ffout, 512, nullptr, nullptr, nullptr, 1024, 0, 0, 0);
    if (l < NL - 1)
      add_ln_k<0><<<M, 256, 0, stream>>>(hb, ffout, g2 + l * 512, be2 + l * 512, nullptr);
    else
      add_ln_k<1><<<M, 256, 0, stream>>>(hb, ffout, g2 + l * 512, be2 + l * 512, h);
  }
}

// Round 6
// 569.984 us; speedup vs baseline: 5.9058x; 1.2465x over previous
//
#include <hip/hip_runtime.h>
#include <math.h>

#define S 512
#define D 512
#define FFD 1024
#define NB 16
#define NL 5

typedef __attribute__((ext_vector_type(8))) short bf16x8;
typedef __attribute__((ext_vector_type(4))) float f32x4;

// ---------------- bf16 helpers ----------------
__device__ __forceinline__ short f2bf(float f){
  union { float f; unsigned u; } c; c.f = f;
  unsigned r = c.u + 0x7FFFu + ((c.u >> 16) & 1u);   // RNE
  return (short)(r >> 16);
}
__device__ __forceinline__ float bf2f(short s){
  union { unsigned u; float f; } c; c.u = ((unsigned)(unsigned short)s) << 16;
  return c.f;
}

// async global->LDS, 16B per lane; lds ptr must be wave-uniform base
__device__ __forceinline__ void gload16(const void* g, void* l){
  __builtin_amdgcn_global_load_lds(
      (const __attribute__((address_space(1))) void*)g,
      (__attribute__((address_space(3))) void*)l, 16, 0, 0);
}

// ---------------- reduction helpers ----------------
__device__ __forceinline__ float wsum(float v){
  #pragma unroll
  for (int o = 32; o; o >>= 1) v += __shfl_down(v, o, 64);
  return v;
}
__device__ __forceinline__ float bsum(float v, float* s){
  v = wsum(v);
  __syncthreads();
  if ((threadIdx.x & 63) == 0) s[threadIdx.x >> 6] = v;
  __syncthreads();
  return s[0] + s[1] + s[2] + s[3];
}

// ---------------- embedding gather (bf16 hb only) ----------------
__global__ __launch_bounds__(256) void embed_k(const int* __restrict__ x,
    const float* __restrict__ tok, short* __restrict__ hb){
  int idx = blockIdx.x * 256 + threadIdx.x;
  int row = idx >> 9;
  int d   = idx & 511;
  hb[idx] = f2bf(tok[x[row] * D + d]);
}

// ---------------- bias concat + brel: bqkv[L][1664] ----------------
__global__ __launch_bounds__(256) void bcat_k(const float* __restrict__ bq,
    const float* __restrict__ bk, const float* __restrict__ bv,
    const float* __restrict__ rel, float* __restrict__ out){
  int i = blockIdx.x * 256 + threadIdx.x;          // L*1664
  if (i >= NL * 1664) return;
  int lay = i / 1664, c = i % 1664;
  float v;
  if      (c <  512) v = bq[lay * 512 + c];
  else if (c < 1024) v = bk[lay * 512 + c - 512];
  else if (c < 1536) v = bv[lay * 512 + c - 1024];
  else if (c < 1547){
    int cc = c - 1536;
    float s = 0.f;
    for (int j = 0; j < 512; j++) s += bq[lay * 512 + j] * rel[cc * 512 + j];
    v = s;
  } else v = 0.f;
  out[i] = v;
}

// ---------------- Wrel: rows 1536..1551 of WqkvT: WrelT[c][k] = Wq[k]·rel[c] ----
__global__ __launch_bounds__(256) void wrel_k(
    const float* __restrict__ Wq, const float* __restrict__ rel,
    short* __restrict__ WqkvT){
  const int bid = blockIdx.x;                      // 5 * 128
  const int lay = bid >> 7, kc = bid & 127;
  const int w = threadIdx.x >> 6, lane = threadIdx.x & 63;
  const int k = kc * 4 + w;
  const float* wrow = Wq + (size_t)lay * 262144 + (size_t)k * 512 + lane * 8;
  float qv[8];
  #pragma unroll
  for (int e = 0; e < 8; e++) qv[e] = wrow[e];
  short* dst = WqkvT + (size_t)lay * 851968;
  #pragma unroll
  for (int c = 0; c < 11; c++){
    const float* rp = rel + c * 512 + lane * 8;
    float s = 0.f;
    #pragma unroll
    for (int e = 0; e < 8; e++) s = fmaf(qv[e], rp[e], s);
    s = wsum(s);
    if (lane == 0) dst[(size_t)(1536 + c) * 512 + k] = f2bf(s);
  }
  if (lane == 0){
    #pragma unroll
    for (int c = 11; c < 16; c++) dst[(size_t)(1536 + c) * 512 + k] = 0;
  }
}

// ---------------- weight transpose + bf16 cast: in[K][N] f32 -> out[N][K] bf16
__global__ __launch_bounds__(256) void wtrans_k(
    const float* __restrict__ Wq, const float* __restrict__ Wk,
    const float* __restrict__ Wv, const float* __restrict__ Wo,
    const float* __restrict__ W1, const float* __restrict__ W2,
    short* __restrict__ WqkvT, short* __restrict__ WoT,
    short* __restrict__ W1T, short* __restrict__ W2T)
{
  __shared__ float tl[64][65];
  int id = blockIdx.x;
  const float* src; short* dst; int K, N, tk, tn;
  if (id < 1280){
    int mat = id / 320, r = id % 320, lay = r / 64, tt = r % 64;
    tk = tt >> 3; tn = tt & 7; K = 512; N = 512;
    const float* s;
    short* d;
    if (mat == 0){ s = Wq; d = WqkvT + (size_t)lay * 851968; }
    else if (mat == 1){ s = Wk; d = WqkvT + (size_t)lay * 851968 + 262144; }
    else if (mat == 2){ s = Wv; d = WqkvT + (size_t)lay * 851968 + 524288; }
    else { s = Wo; d = WoT + (size_t)lay * 262144; }
    src = s + (size_t)lay * 262144; dst = d;
  } else if (id < 1920){
    int r = id - 1280, lay = r / 128, tt = r % 128;
    tk = tt >> 4; tn = tt & 15; K = 512; N = 1024;
    src = W1 + (size_t)lay * 524288; dst = W1T + (size_t)lay * 524288;
  } else {
    int r = id - 1920, lay = r / 128, tt = r % 128;
    tk = tt >> 3; tn = tt & 7; K = 1024; N = 512;
    src = W2 + (size_t)lay * 524288; dst = W2T + (size_t)lay * 524288;
  }
  const int k0 = tk * 64, n0 = tn * 64;
  const int t = threadIdx.x;
  const int lr = t >> 4, lc = (t & 15) * 4;
  #pragma unroll
  for (int s = 0; s < 4; s++){
    int row = lr + s * 16;
    float4 v = *(const float4*)&src[(size_t)(k0 + row) * N + n0 + lc];
    tl[row][lc + 0] = v.x; tl[row][lc + 1] = v.y;
    tl[row][lc + 2] = v.z; tl[row][lc + 3] = v.w;
  }
  __syncthreads();
  const int nr8 = t >> 3, kc8 = (t & 7) * 8;
  #pragma unroll
  for (int s = 0; s < 2; s++){
    int nr = nr8 + s * 32;
    bf16x8 o;
    #pragma unroll
    for (int e = 0; e < 8; e++) o[e] = f2bf(tl[kc8 + e][nr]);
    *(bf16x8*)&dst[(size_t)(n0 + nr) * K + k0 + kc8] = o;
  }
}

// ---------------- staging: ROWS x (PAN*32) bf16 tile, panel-major LDS ----------------
template<int ROWS, int PAN>
__device__ __forceinline__ void stage_tile(const short* __restrict__ G, int ld,
                                           int kbase, char* ldsBase, int w, int l){
  constexpr int CALLS = ROWS * PAN / 64;   // per-wave gload16 calls
  #pragma unroll
  for (int c = 0; c < CALLS; c++){
    const int idx = w * CALLS + c;
    const int panel = idx / (ROWS / 16);
    const int chunk = idx % (ROWS / 16);
    const short* src = G + (size_t)(chunk * 16 + (l >> 2)) * ld
                         + kbase + panel * 32 + (l & 3) * 8;
    gload16(src, ldsBase + idx * 1024);
  }
}

// ---------------- generic MFMA NT GEMM, BMxBN tile, BK in {32,64}, 2-phase dbuf ----
// MODE: 1 bf16+bias, 2 bf16+bias+relu, 3 scores->exp->bf16 p, 4 PV+normalize,
//       5 QKV fused (qkv | vT | qrel)
// Epilogue: LDS-bounce -> coalesced bf16x8 stores. XCD-swizzled block ids.
template<int BM, int BN, int MODE, int BK>
__global__ __launch_bounds__(256) void mm_nt(
    const short* __restrict__ A, int ldA,
    const short* __restrict__ B, int ldB,
    const float* __restrict__ bias, void* __restrict__ C, int ldC,
    const float* __restrict__ qrel, short* __restrict__ vT,
    float* __restrict__ qrelOut,
    int K, long batA, long batB, long batC)
{
  constexpr int PAN = BK / 32;
  constexpr int STAGE_SH = 2 * BK * (BM + BN);
  constexpr int BOUNCE_SH = BM * BN;
  constexpr int SMEM_SH = STAGE_SH > BOUNCE_SH ? STAGE_SH : BOUNCE_SH;
  __shared__ short smem[SMEM_SH];
  short* As = smem;
  short* Bs = smem + 2 * BM * BK;

  // XCD-aware bijective swizzle (all launched grids have nwg % 8 == 0)
  const int gx = gridDim.x, gy = gridDim.y;
  int flat = ((int)blockIdx.z * gy + (int)blockIdx.y) * gx + (int)blockIdx.x;
  const int nwg = gx * gy * (int)gridDim.z;
  const int chunk = nwg >> 3;
  flat = (flat & 7) * chunk + (flat >> 3);
  const int bx = flat % gx;
  const int byy = (flat / gx) % gy;
  const int b = flat / (gx * gy);

  const int m0 = byy * BM, n0 = bx * BN;
  if (MODE == 3 && n0 > m0) return;          // tile fully above causal diagonal
  int nk = K / BK;
  if (MODE == 4){ int km = (m0 + BM) / BK; nk = km < nk ? km : nk; }

  constexpr int FM = BM / 32, FN = BN / 32;
  f32x4 acc[FM][FN];
  const f32x4 z = {0.f, 0.f, 0.f, 0.f};
  #pragma unroll
  for (int m = 0; m < FM; m++)
    #pragma unroll
    for (int n = 0; n < FN; n++) acc[m][n] = z;

  const int t = threadIdx.x, l = t & 63, w = t >> 6;
  const short* Ag = A + (size_t)b * batA + (size_t)m0 * ldA;
  const short* Bg = B + (size_t)b * batB + (size_t)n0 * ldB;

  stage_tile<BM, PAN>(Ag, ldA, 0, (char*)As, w, l);
  stage_tile<BN, PAN>(Bg, ldB, 0, (char*)Bs, w, l);
  __syncthreads();

  const int wm = (w >> 1) * (BM / 2), wn = (w & 1) * (BN / 2);
  const int kc = (l >> 4) * 8;
  float rs[FM];
  #pragma unroll
  for (int m = 0; m < FM; m++) rs[m] = 0.f;

  for (int ks = 0; ks < nk; ks++){
    const int cur = ks & 1;
    if (ks + 1 < nk){
      const int nxt = cur ^ 1;
      stage_tile<BM, PAN>(Ag, ldA, (ks + 1) * BK, (char*)As + nxt * (BM * BK * 2), w, l);
      stage_tile<BN, PAN>(Bg, ldB, (ks + 1) * BK, (char*)Bs + nxt * (BN * BK * 2), w, l);
    }
    const short* Ab = As + cur * (BM * BK);
    const short* Bb = Bs + cur * (BN * BK);
    #pragma unroll
    for (int p = 0; p < PAN; p++){
      bf16x8 af[FM], bfr[FN];
      #pragma unroll
      for (int m = 0; m < FM; m++)
        af[m] = *(const bf16x8*)&Ab[p * BM * 32 + (wm + m * 16 + (l & 15)) * 32 + kc];
      #pragma unroll
      for (int n = 0; n < FN; n++)
        bfr[n] = *(const bf16x8*)&Bb[p * BN * 32 + (wn + n * 16 + (l & 15)) * 32 + kc];
      if (MODE == 4){
        #pragma unroll
        for (int m = 0; m < FM; m++){
          float s = 0.f;
          #pragma unroll
          for (int e = 0; e < 8; e++) s += bf2f(af[m][e]);
          rs[m] += s;
        }
      }
      #pragma unroll
      for (int m = 0; m < FM; m++)
        #pragma unroll
        for (int n = 0; n < FN; n++)
          acc[m][n] = __builtin_amdgcn_mfma_f32_16x16x32_bf16(af[m], bfr[n], acc[m][n], 0, 0, 0);
    }
    __syncthreads();
  }

  float invr[FM][4];
  if (MODE == 4){
    #pragma unroll
    for (int m = 0; m < FM; m++){
      float r = rs[m];
      r += __shfl_xor(r, 16, 64);
      r += __shfl_xor(r, 32, 64);
      #pragma unroll
      for (int rr = 0; rr < 4; rr++)
        invr[m][rr] = 1.0f / __shfl(r, (l >> 4) * 4 + rr, 64);
    }
  }

  const size_t cbase = (size_t)b * batC;

  if (MODE == 5 && n0 >= 1024){
    if (n0 < 1536){
      // V^T tiles: vT[b][d][s], 4 consecutive s per lane -> 8B store
      #pragma unroll
      for (int m = 0; m < FM; m++){
        const int rbase = m0 + wm + m * 16 + (l >> 4) * 4;
        #pragma unroll
        for (int n = 0; n < FN; n++){
          const int col = n0 + wn + n * 16 + (l & 15);
          const int d = col - 1024;
          const int bb = rbase >> 9, s0 = rbase & 511;
          union { short s[4]; uint2 u; } tmp;
          #pragma unroll
          for (int r = 0; r < 4; r++) tmp.s[r] = f2bf(acc[m][n][r] + bias[col]);
          *(uint2*)&vT[(size_t)bb * 262144 + (size_t)d * 512 + s0] = tmp.u;
        }
      }
    } else {
      // qrel tile: cols 1536..1551 used
      #pragma unroll
      for (int m = 0; m < FM; m++){
        const int rbase = m0 + wm + m * 16 + (l >> 4) * 4;
        #pragma unroll
        for (int n = 0; n < FN; n++){
          const int col = n0 + wn + n * 16 + (l & 15);
          if (col < 1552){
            const int c = col - 1536;
            #pragma unroll
            for (int r = 0; r < 4; r++)
              qrelOut[(size_t)(rbase + r) * 16 + c] = acc[m][n][r] + bias[col];
          }
        }
      }
    }
    return;
  }

  // ---- LDS-bounce epilogue (safe: all waves passed the loop's final barrier) ----
  #pragma unroll
  for (int m = 0; m < FM; m++){
    const int rb = wm + m * 16 + (l >> 4) * 4;
    #pragma unroll
    for (int n = 0; n < FN; n++){
      const int cl = wn + n * 16 + (l & 15);
      const int col = n0 + cl;
      #pragma unroll
      for (int r = 0; r < 4; r++){
        const int row = m0 + rb + r;
        float v = acc[m][n][r];
        short ov;
        if (MODE == 3){
          if (col <= row){
            int dd = row - col; if (dd > 10) dd = 10;
            float sv = v * (1.0f / 512.0f)
                     + qrel[((size_t)b * S + row) * 16 + dd] * 0.044194173824159216f;
            ov = f2bf(__expf(sv));
          } else ov = 0;
        } else if (MODE == 4){
          ov = f2bf(v * invr[m][r]);
        } else {
          v += bias[col];
          if (MODE == 2) v = fmaxf(v, 0.f);
          ov = f2bf(v);
        }
        smem[(rb + r) * BN + cl] = ov;
      }
    }
  }
  __syncthreads();
  constexpr int ITER = BM * BN / 2048;
  #pragma unroll
  for (int c = 0; c < ITER; c++){
    const int idx = c * 2048 + t * 8;
    const int row = idx / BN, cc = idx % BN;
    *(bf16x8*)&((short*)C)[cbase + (size_t)(m0 + row) * ldC + n0 + cc] =
        *(const bf16x8*)&smem[idx];
  }
}

// ---------------- h = LN(h + y), bf16 residual; FINAL writes f32 out ----------
template<int FINAL>
__global__ __launch_bounds__(256) void add_ln_k(
    short* __restrict__ hb, const short* __restrict__ y,
    const float* __restrict__ g, const float* __restrict__ be,
    float* __restrict__ hOut)
{
  __shared__ float red[4];
  const int row = blockIdx.x;
  short* hbr = hb + (size_t)row * D;
  const short* yr = y + (size_t)row * D;
  const int t = threadIdx.x;
  float v0 = bf2f(hbr[t])       + bf2f(yr[t]);
  float v1 = bf2f(hbr[t + 256]) + bf2f(yr[t + 256]);
  float mu = bsum(v0 + v1, red) * (1.0f / 512.0f);
  float d0 = v0 - mu, d1 = v1 - mu;
  float var = bsum(d0 * d0 + d1 * d1, red) * (1.0f / 512.0f);
  float rcp = rsqrtf(var + 1e-5f);
  float o0 = d0 * rcp * g[t]       + be[t];
  float o1 = d1 * rcp * g[t + 256] + be[t + 256];
  if (FINAL){
    float* ho = hOut + (size_t)row * D;
    ho[t]       = o0;
    ho[t + 256] = o1;
  } else {
    hbr[t]       = f2bf(o0);
    hbr[t + 256] = f2bf(o1);
  }
}

// ---------------- driver ----------------
extern "C" void kernel_launch(void* const* d_in, const int* in_sizes, int n_in,
                              void* d_out, int out_size, void* d_ws, size_t ws_size,
                              hipStream_t stream)
{
  const int*   x   = (const int*)  d_in[0];
  const float* tok = (const float*)d_in[1];
  const float* rel = (const float*)d_in[2];
  const float* Wq  = (const float*)d_in[3];  const float* bq = (const float*)d_in[4];
  const float* Wk  = (const float*)d_in[5];  const float* bk = (const float*)d_in[6];
  const float* Wv  = (const float*)d_in[7];  const float* bv = (const float*)d_in[8];
  const float* Wo  = (const float*)d_in[9];  const float* bo = (const float*)d_in[10];
  const float* W1  = (const float*)d_in[11]; const float* b1 = (const float*)d_in[12];
  const float* W2  = (const float*)d_in[13]; const float* b2 = (const float*)d_in[14];
  const float* g1  = (const float*)d_in[15]; const float* be1 = (const float*)d_in[16];
  const float* g2  = (const float*)d_in[17]; const float* be2 = (const float*)d_in[18];
  (void)in_sizes; (void)n_in; (void)out_size; (void)ws_size;

  float* h = (float*)d_out;                  // final f32 output only

  char* ws = (char*)d_ws;
  const size_t MB = 1 << 20;
  short* hb     = (short*)(ws);              // 8MB  bf16 residual stream
  short* qkv    = (short*)(ws + 8 * MB);     // 16MB [M][1024] (q|k)
  short* vT     = (short*)(ws + 24 * MB);    // 8MB  [b][D][S]
  short* p      = (short*)(ws + 32 * MB);    // 8MB  unnormalized exp scores
  short* ctx    = (short*)(ws + 40 * MB);    // 8MB
  short* xatt   = (short*)(ws + 48 * MB);    // 8MB (also ffout)
  short* ffmid  = (short*)(ws + 32 * MB);    // 16MB spans p+ctx (dead by FFN1)
  float* qrelb  = (float*)(ws + 56 * MB);    // 512KB [M][16] f32
  float* bqkv   = (float*)(ws + 56 * MB + 512 * 1024);  // L*1664*4 = 33KB
  short* wb     = (short*)(ws + 57 * MB);
  short* WqkvT  = wb;                                   // L*1664*512 bf16
  short* WoT    = WqkvT + (size_t)5 * 851968;           // L*512*512
  short* W1T    = WoT   + (size_t)5 * 262144;           // L*512*1024
  short* W2T    = W1T   + (size_t)5 * 524288;           // L*1024*512
  short* ffout  = xatt;

  const int M = NB * S;                      // 8192

  wtrans_k<<<2560, 256, 0, stream>>>(Wq, Wk, Wv, Wo, W1, W2, WqkvT, WoT, W1T, W2T);
  wrel_k<<<640, 256, 0, stream>>>(Wq, rel, WqkvT);
  bcat_k<<<(NL * 1664 + 255) / 256, 256, 0, stream>>>(bq, bk, bv, rel, bqkv);
  embed_k<<<(size_t)M * D / 256, 256, 0, stream>>>(x, tok, hb);

  for (int l = 0; l < NL; l++){
    // fused QKV+qrel: q,k -> qkv[M][1024]; v -> vT; qrel -> qrelb
    mm_nt<128, 128, 5, 32><<<dim3(13, 64, 1), 256, 0, stream>>>(
        hb, 512, WqkvT + (size_t)l * 851968, 512, bqkv + l * 1664,
        qkv, 1024, nullptr, vT, qrelb, 512, 0, 0, 0);

    // scores -> exp -> p (unnormalized, zeros above diagonal)
    mm_nt<64, 64, 3, 64><<<dim3(8, 8, NB), 256, 0, stream>>>(
        qkv, 1024, qkv + 512, 1024, nullptr,
        p, 512, qrelb, nullptr, nullptr, 512,
        (long)S * 1024, (long)S * 1024, (long)S * S);

    // PV + row-sum normalize
    mm_nt<64, 64, 4, 64><<<dim3(8, 8, NB), 256, 0, stream>>>(
        p, 512, vT, 512, nullptr,
        ctx, 512, nullptr, nullptr, nullptr, 512,
        (long)S * S, (long)D * S, (long)S * D);

    mm_nt<128, 64, 1, 64><<<dim3(8, 64, 1), 256, 0, stream>>>(
        ctx, 512, WoT + (size_t)l * 262144, 512, bo + l * 512,
        xatt, 512, nullptr, nullptr, nullptr, 512, 0, 0, 0);
    add_ln_k<0><<<M, 256, 0, stream>>>(hb, xatt, g1 + l * 512, be1 + l * 512, nullptr);

    mm_nt<128, 128, 2, 32><<<dim3(8, 64, 1), 256, 0, stream>>>(
        hb, 512, W1T + (size_t)l * 524288, 512, b1 + l * 1024,
        ffmid, 1024, nullptr, nullptr, nullptr, 512, 0, 0, 0);
    mm_nt<128, 64, 1, 64><<<dim3(8, 64, 1), 256, 0, stream>>>(
        ffmid, 1024, W2T + (size_t)l * 524288, 1024, b2 + l * 512,
        ffout, 512, nullptr, nullptr, nullptr, 1024, 0, 0, 0);
    if (l < NL - 1)
      add_ln_k<0><<<M, 256, 0, stream>>>(hb, ffout, g2 + l * 512, be2 + l * 512, nullptr);
    else
      add_ln_k<1><<<M, 256, 0, stream>>>(hb, ffout, g2 + l * 512, be2 + l * 512, h);
  }
}

// Round 7
// 538.688 us; speedup vs baseline: 6.2489x; 1.0581x over previous
//
#include <hip/hip_runtime.h>
#include <math.h>

#define S 512
#define D 512
#define FFD 1024
#define NB 16
#define NL 5

typedef __attribute__((ext_vector_type(8))) short bf16x8;
typedef __attribute__((ext_vector_type(4))) float f32x4;

// ---------------- bf16 helpers ----------------
__device__ __forceinline__ short f2bf(float f){
  union { float f; unsigned u; } c; c.f = f;
  unsigned r = c.u + 0x7FFFu + ((c.u >> 16) & 1u);   // RNE
  return (short)(r >> 16);
}
__device__ __forceinline__ float bf2f(short s){
  union { unsigned u; float f; } c; c.u = ((unsigned)(unsigned short)s) << 16;
  return c.f;
}

// async global->LDS, 16B per lane; lds ptr must be wave-uniform base
__device__ __forceinline__ void gload16(const void* g, void* l){
  __builtin_amdgcn_global_load_lds(
      (const __attribute__((address_space(1))) void*)g,
      (__attribute__((address_space(3))) void*)l, 16, 0, 0);
}

// ---------------- reduction helpers ----------------
__device__ __forceinline__ float wsum(float v){
  #pragma unroll
  for (int o = 32; o; o >>= 1) v += __shfl_down(v, o, 64);
  return v;
}

// ---------------- embedding gather (bf16 hb only) ----------------
__global__ __launch_bounds__(256) void embed_k(const int* __restrict__ x,
    const float* __restrict__ tok, short* __restrict__ hb){
  int idx = blockIdx.x * 256 + threadIdx.x;
  int row = idx >> 9;
  int d   = idx & 511;
  hb[idx] = f2bf(tok[x[row] * D + d]);
}

// ---------------- bias concat + brel: bqkv[L][1664] ----------------
__global__ __launch_bounds__(256) void bcat_k(const float* __restrict__ bq,
    const float* __restrict__ bk, const float* __restrict__ bv,
    const float* __restrict__ rel, float* __restrict__ out){
  int i = blockIdx.x * 256 + threadIdx.x;          // L*1664
  if (i >= NL * 1664) return;
  int lay = i / 1664, c = i % 1664;
  float v;
  if      (c <  512) v = bq[lay * 512 + c];
  else if (c < 1024) v = bk[lay * 512 + c - 512];
  else if (c < 1536) v = bv[lay * 512 + c - 1024];
  else if (c < 1547){
    int cc = c - 1536;
    float s = 0.f;
    for (int j = 0; j < 512; j++) s += bq[lay * 512 + j] * rel[cc * 512 + j];
    v = s;
  } else v = 0.f;
  out[i] = v;
}

// ---------------- Wrel: rows 1536..1551 of WqkvT: WrelT[c][k] = Wq[k]·rel[c] ----
__global__ __launch_bounds__(256) void wrel_k(
    const float* __restrict__ Wq, const float* __restrict__ rel,
    short* __restrict__ WqkvT){
  const int bid = blockIdx.x;                      // 5 * 128
  const int lay = bid >> 7, kc = bid & 127;
  const int w = threadIdx.x >> 6, lane = threadIdx.x & 63;
  const int k = kc * 4 + w;
  const float* wrow = Wq + (size_t)lay * 262144 + (size_t)k * 512 + lane * 8;
  float qv[8];
  #pragma unroll
  for (int e = 0; e < 8; e++) qv[e] = wrow[e];
  short* dst = WqkvT + (size_t)lay * 851968;
  #pragma unroll
  for (int c = 0; c < 11; c++){
    const float* rp = rel + c * 512 + lane * 8;
    float s = 0.f;
    #pragma unroll
    for (int e = 0; e < 8; e++) s = fmaf(qv[e], rp[e], s);
    s = wsum(s);
    if (lane == 0) dst[(size_t)(1536 + c) * 512 + k] = f2bf(s);
  }
  if (lane == 0){
    #pragma unroll
    for (int c = 11; c < 16; c++) dst[(size_t)(1536 + c) * 512 + k] = 0;
  }
}

// ---------------- weight transpose + bf16 cast: in[K][N] f32 -> out[N][K] bf16
__global__ __launch_bounds__(256) void wtrans_k(
    const float* __restrict__ Wq, const float* __restrict__ Wk,
    const float* __restrict__ Wv, const float* __restrict__ Wo,
    const float* __restrict__ W1, const float* __restrict__ W2,
    short* __restrict__ WqkvT, short* __restrict__ WoT,
    short* __restrict__ W1T, short* __restrict__ W2T)
{
  __shared__ float tl[64][65];
  int id = blockIdx.x;
  const float* src; short* dst; int K, N, tk, tn;
  if (id < 1280){
    int mat = id / 320, r = id % 320, lay = r / 64, tt = r % 64;
    tk = tt >> 3; tn = tt & 7; K = 512; N = 512;
    const float* s;
    short* d;
    if (mat == 0){ s = Wq; d = WqkvT + (size_t)lay * 851968; }
    else if (mat == 1){ s = Wk; d = WqkvT + (size_t)lay * 851968 + 262144; }
    else if (mat == 2){ s = Wv; d = WqkvT + (size_t)lay * 851968 + 524288; }
    else { s = Wo; d = WoT + (size_t)lay * 262144; }
    src = s + (size_t)lay * 262144; dst = d;
  } else if (id < 1920){
    int r = id - 1280, lay = r / 128, tt = r % 128;
    tk = tt >> 4; tn = tt & 15; K = 512; N = 1024;
    src = W1 + (size_t)lay * 524288; dst = W1T + (size_t)lay * 524288;
  } else {
    int r = id - 1920, lay = r / 128, tt = r % 128;
    tk = tt >> 3; tn = tt & 7; K = 1024; N = 512;
    src = W2 + (size_t)lay * 524288; dst = W2T + (size_t)lay * 524288;
  }
  const int k0 = tk * 64, n0 = tn * 64;
  const int t = threadIdx.x;
  const int lr = t >> 4, lc = (t & 15) * 4;
  #pragma unroll
  for (int s = 0; s < 4; s++){
    int row = lr + s * 16;
    float4 v = *(const float4*)&src[(size_t)(k0 + row) * N + n0 + lc];
    tl[row][lc + 0] = v.x; tl[row][lc + 1] = v.y;
    tl[row][lc + 2] = v.z; tl[row][lc + 3] = v.w;
  }
  __syncthreads();
  const int nr8 = t >> 3, kc8 = (t & 7) * 8;
  #pragma unroll
  for (int s = 0; s < 2; s++){
    int nr = nr8 + s * 32;
    bf16x8 o;
    #pragma unroll
    for (int e = 0; e < 8; e++) o[e] = f2bf(tl[kc8 + e][nr]);
    *(bf16x8*)&dst[(size_t)(n0 + nr) * K + k0 + kc8] = o;
  }
}

// ---------------- staging: ROWS x (PAN*32) bf16 tile, panel-major LDS ----------------
template<int ROWS, int PAN>
__device__ __forceinline__ void stage_tile(const short* __restrict__ G, int ld,
                                           int kbase, char* ldsBase, int w, int l){
  constexpr int CALLS = ROWS * PAN / 64;   // per-wave gload16 calls
  #pragma unroll
  for (int c = 0; c < CALLS; c++){
    const int idx = w * CALLS + c;
    const int panel = idx / (ROWS / 16);
    const int chunk = idx % (ROWS / 16);
    const short* src = G + (size_t)(chunk * 16 + (l >> 2)) * ld
                         + kbase + panel * 32 + (l & 3) * 8;
    gload16(src, ldsBase + idx * 1024);
  }
}

// ---------------- generic MFMA NT GEMM, BMxBN tile, BK in {32,64}, 2-phase dbuf ----
// MODE: 1 bf16+bias, 2 bf16+bias+relu, 3 scores->exp->bf16 p, 4 PV+normalize,
//       5 QKV fused (qkv | vT | qrel)
// Epilogue: LDS-bounce -> coalesced bf16x8 stores. XCD-swizzled block ids.
template<int BM, int BN, int MODE, int BK>
__global__ __launch_bounds__(256) void mm_nt(
    const short* __restrict__ A, int ldA,
    const short* __restrict__ B, int ldB,
    const float* __restrict__ bias, void* __restrict__ C, int ldC,
    const float* __restrict__ qrel, short* __restrict__ vT,
    float* __restrict__ qrelOut,
    int K, long batA, long batB, long batC)
{
  constexpr int PAN = BK / 32;
  constexpr int STAGE_SH = 2 * BK * (BM + BN);
  constexpr int BOUNCE_SH = BM * BN;
  constexpr int TB_ST = BM + 8;                       // padded transposed stride
  constexpr int TBOUNCE_SH = (MODE == 5) ? BN * TB_ST : 0;
  constexpr int SMEM_A = STAGE_SH > BOUNCE_SH ? STAGE_SH : BOUNCE_SH;
  constexpr int SMEM_SH = SMEM_A > TBOUNCE_SH ? SMEM_A : TBOUNCE_SH;
  __shared__ short smem[SMEM_SH];
  short* As = smem;
  short* Bs = smem + 2 * BM * BK;

  // XCD-aware bijective swizzle (all launched grids have nwg % 8 == 0)
  const int gx = gridDim.x, gy = gridDim.y;
  int flat = ((int)blockIdx.z * gy + (int)blockIdx.y) * gx + (int)blockIdx.x;
  const int nwg = gx * gy * (int)gridDim.z;
  const int chunk = nwg >> 3;
  flat = (flat & 7) * chunk + (flat >> 3);
  const int bx = flat % gx;
  const int byy = (flat / gx) % gy;
  const int b = flat / (gx * gy);

  const int m0 = byy * BM, n0 = bx * BN;
  if (MODE == 3 && n0 >= m0 + BM) return;    // tile fully above causal diagonal
  int nk = K / BK;
  if (MODE == 4){ int km = (m0 + BM) / BK; nk = km < nk ? km : nk; }

  constexpr int FM = BM / 32, FN = BN / 32;
  f32x4 acc[FM][FN];
  const f32x4 z = {0.f, 0.f, 0.f, 0.f};
  #pragma unroll
  for (int m = 0; m < FM; m++)
    #pragma unroll
    for (int n = 0; n < FN; n++) acc[m][n] = z;

  const int t = threadIdx.x, l = t & 63, w = t >> 6;
  const short* Ag = A + (size_t)b * batA + (size_t)m0 * ldA;
  const short* Bg = B + (size_t)b * batB + (size_t)n0 * ldB;

  stage_tile<BM, PAN>(Ag, ldA, 0, (char*)As, w, l);
  stage_tile<BN, PAN>(Bg, ldB, 0, (char*)Bs, w, l);
  __syncthreads();

  const int wm = (w >> 1) * (BM / 2), wn = (w & 1) * (BN / 2);
  const int kc = (l >> 4) * 8;
  float rs[FM];
  #pragma unroll
  for (int m = 0; m < FM; m++) rs[m] = 0.f;

  for (int ks = 0; ks < nk; ks++){
    const int cur = ks & 1;
    if (ks + 1 < nk){
      const int nxt = cur ^ 1;
      stage_tile<BM, PAN>(Ag, ldA, (ks + 1) * BK, (char*)As + nxt * (BM * BK * 2), w, l);
      stage_tile<BN, PAN>(Bg, ldB, (ks + 1) * BK, (char*)Bs + nxt * (BN * BK * 2), w, l);
    }
    const short* Ab = As + cur * (BM * BK);
    const short* Bb = Bs + cur * (BN * BK);
    #pragma unroll
    for (int p = 0; p < PAN; p++){
      bf16x8 af[FM], bfr[FN];
      #pragma unroll
      for (int m = 0; m < FM; m++)
        af[m] = *(const bf16x8*)&Ab[p * BM * 32 + (wm + m * 16 + (l & 15)) * 32 + kc];
      #pragma unroll
      for (int n = 0; n < FN; n++)
        bfr[n] = *(const bf16x8*)&Bb[p * BN * 32 + (wn + n * 16 + (l & 15)) * 32 + kc];
      if (MODE == 4){
        #pragma unroll
        for (int m = 0; m < FM; m++){
          float s = 0.f;
          #pragma unroll
          for (int e = 0; e < 8; e++) s += bf2f(af[m][e]);
          rs[m] += s;
        }
      }
      #pragma unroll
      for (int m = 0; m < FM; m++)
        #pragma unroll
        for (int n = 0; n < FN; n++)
          acc[m][n] = __builtin_amdgcn_mfma_f32_16x16x32_bf16(af[m], bfr[n], acc[m][n], 0, 0, 0);
    }
    __syncthreads();
  }

  float invr[FM][4];
  if (MODE == 4){
    #pragma unroll
    for (int m = 0; m < FM; m++){
      float r = rs[m];
      r += __shfl_xor(r, 16, 64);
      r += __shfl_xor(r, 32, 64);
      #pragma unroll
      for (int rr = 0; rr < 4; rr++)
        invr[m][rr] = 1.0f / __shfl(r, (l >> 4) * 4 + rr, 64);
    }
  }

  const size_t cbase = (size_t)b * batC;

  if (MODE == 5 && n0 >= 1024){
    if (n0 < 1536){
      // V^T tiles via transposed LDS bounce: smem_t[d_local][s_local], padded.
      short* tb = smem;
      #pragma unroll
      for (int m = 0; m < FM; m++){
        const int rb = wm + m * 16 + (l >> 4) * 4;        // s_local base (mult of 4)
        #pragma unroll
        for (int n = 0; n < FN; n++){
          const int cl = wn + n * 16 + (l & 15);          // d_local
          const int col = n0 + cl;
          union { short s[4]; uint2 u; } tmp;
          #pragma unroll
          for (int r = 0; r < 4; r++) tmp.s[r] = f2bf(acc[m][n][r] + bias[col]);
          *(uint2*)&tb[cl * TB_ST + rb] = tmp.u;
        }
      }
      __syncthreads();
      const int dbase = n0 - 1024;
      constexpr int ITER_T = BM * BN / 2048;
      #pragma unroll
      for (int c = 0; c < ITER_T; c++){
        const int idx = c * 2048 + t * 8;
        const int dl = idx / BM, sl = idx % BM;
        const int grow = m0 + sl;
        const int bb = grow >> 9, s0 = grow & 511;
        *(bf16x8*)&vT[(size_t)bb * 262144 + (size_t)(dbase + dl) * 512 + s0] =
            *(const bf16x8*)&tb[dl * TB_ST + sl];
      }
      return;
    } else {
      // qrel tile: cols 1536..1551 used
      #pragma unroll
      for (int m = 0; m < FM; m++){
        const int rbase = m0 + wm + m * 16 + (l >> 4) * 4;
        #pragma unroll
        for (int n = 0; n < FN; n++){
          const int col = n0 + wn + n * 16 + (l & 15);
          if (col < 1552){
            const int c = col - 1536;
            #pragma unroll
            for (int r = 0; r < 4; r++)
              qrelOut[(size_t)(rbase + r) * 16 + c] = acc[m][n][r] + bias[col];
          }
        }
      }
      return;
    }
  }

  // ---- LDS-bounce epilogue (safe: all waves passed the loop's final barrier) ----
  #pragma unroll
  for (int m = 0; m < FM; m++){
    const int rb = wm + m * 16 + (l >> 4) * 4;
    #pragma unroll
    for (int n = 0; n < FN; n++){
      const int cl = wn + n * 16 + (l & 15);
      const int col = n0 + cl;
      #pragma unroll
      for (int r = 0; r < 4; r++){
        const int row = m0 + rb + r;
        float v = acc[m][n][r];
        short ov;
        if (MODE == 3){
          if (col <= row){
            int dd = row - col; if (dd > 10) dd = 10;
            float sv = v * (1.0f / 512.0f)
                     + qrel[((size_t)b * S + row) * 16 + dd] * 0.044194173824159216f;
            ov = f2bf(__expf(sv));
          } else ov = 0;
        } else if (MODE == 4){
          ov = f2bf(v * invr[m][r]);
        } else {
          v += bias[col];
          if (MODE == 2) v = fmaxf(v, 0.f);
          ov = f2bf(v);
        }
        smem[(rb + r) * BN + cl] = ov;
      }
    }
  }
  __syncthreads();
  constexpr int ITER = BM * BN / 2048;
  #pragma unroll
  for (int c = 0; c < ITER; c++){
    const int idx = c * 2048 + t * 8;
    const int row = idx / BN, cc = idx % BN;
    *(bf16x8*)&((short*)C)[cbase + (size_t)(m0 + row) * ldC + n0 + cc] =
        *(const bf16x8*)&smem[idx];
  }
}

// ---------------- h = LN(h + y): one wave per row, no barriers ----------------
template<int FINAL>
__global__ __launch_bounds__(256) void add_ln_k(
    short* __restrict__ hb, const short* __restrict__ y,
    const float* __restrict__ g, const float* __restrict__ be,
    float* __restrict__ hOut)
{
  const int t = threadIdx.x, w = t >> 6, l = t & 63;
  const int row = blockIdx.x * 4 + w;
  short* hbr = hb + (size_t)row * D;
  const short* yr = y + (size_t)row * D;
  bf16x8 h8 = *(const bf16x8*)&hbr[l * 8];
  bf16x8 y8 = *(const bf16x8*)&yr[l * 8];
  float v[8], s1 = 0.f, s2 = 0.f;
  #pragma unroll
  for (int e = 0; e < 8; e++){
    v[e] = bf2f(h8[e]) + bf2f(y8[e]);
    s1 += v[e];
    s2 += v[e] * v[e];
  }
  #pragma unroll
  for (int o = 32; o; o >>= 1){
    s1 += __shfl_xor(s1, o, 64);
    s2 += __shfl_xor(s2, o, 64);
  }
  const float mu  = s1 * (1.0f / 512.0f);
  const float var = s2 * (1.0f / 512.0f) - mu * mu;
  const float rcp = rsqrtf(var + 1e-5f);
  float4 g0 = *(const float4*)&g[l * 8];
  float4 g1 = *(const float4*)&g[l * 8 + 4];
  float4 b0 = *(const float4*)&be[l * 8];
  float4 b1 = *(const float4*)&be[l * 8 + 4];
  float gv[8] = {g0.x, g0.y, g0.z, g0.w, g1.x, g1.y, g1.z, g1.w};
  float bv[8] = {b0.x, b0.y, b0.z, b0.w, b1.x, b1.y, b1.z, b1.w};
  float o[8];
  #pragma unroll
  for (int e = 0; e < 8; e++) o[e] = (v[e] - mu) * rcp * gv[e] + bv[e];
  if (FINAL){
    float* ho = hOut + (size_t)row * D + l * 8;
    *(float4*)&ho[0] = make_float4(o[0], o[1], o[2], o[3]);
    *(float4*)&ho[4] = make_float4(o[4], o[5], o[6], o[7]);
  } else {
    bf16x8 ob;
    #pragma unroll
    for (int e = 0; e < 8; e++) ob[e] = f2bf(o[e]);
    *(bf16x8*)&hbr[l * 8] = ob;
  }
}

// ---------------- driver ----------------
extern "C" void kernel_launch(void* const* d_in, const int* in_sizes, int n_in,
                              void* d_out, int out_size, void* d_ws, size_t ws_size,
                              hipStream_t stream)
{
  const int*   x   = (const int*)  d_in[0];
  const float* tok = (const float*)d_in[1];
  const float* rel = (const float*)d_in[2];
  const float* Wq  = (const float*)d_in[3];  const float* bq = (const float*)d_in[4];
  const float* Wk  = (const float*)d_in[5];  const float* bk = (const float*)d_in[6];
  const float* Wv  = (const float*)d_in[7];  const float* bv = (const float*)d_in[8];
  const float* Wo  = (const float*)d_in[9];  const float* bo = (const float*)d_in[10];
  const float* W1  = (const float*)d_in[11]; const float* b1 = (const float*)d_in[12];
  const float* W2  = (const float*)d_in[13]; const float* b2 = (const float*)d_in[14];
  const float* g1  = (const float*)d_in[15]; const float* be1 = (const float*)d_in[16];
  const float* g2  = (const float*)d_in[17]; const float* be2 = (const float*)d_in[18];
  (void)in_sizes; (void)n_in; (void)out_size; (void)ws_size;

  float* h = (float*)d_out;                  // final f32 output only

  char* ws = (char*)d_ws;
  const size_t MB = 1 << 20;
  short* hb     = (short*)(ws);              // 8MB  bf16 residual stream
  short* qkv    = (short*)(ws + 8 * MB);     // 16MB [M][1024] (q|k)
  short* vT     = (short*)(ws + 24 * MB);    // 8MB  [b][D][S]
  short* p      = (short*)(ws + 32 * MB);    // 8MB  unnormalized exp scores
  short* ctx    = (short*)(ws + 40 * MB);    // 8MB
  short* xatt   = (short*)(ws + 48 * MB);    // 8MB (also ffout)
  short* ffmid  = (short*)(ws + 32 * MB);    // 16MB spans p+ctx (dead by FFN1)
  float* qrelb  = (float*)(ws + 56 * MB);    // 512KB [M][16] f32
  float* bqkv   = (float*)(ws + 56 * MB + 512 * 1024);  // L*1664*4 = 33KB
  short* wb     = (short*)(ws + 57 * MB);
  short* WqkvT  = wb;                                   // L*1664*512 bf16
  short* WoT    = WqkvT + (size_t)5 * 851968;           // L*512*512
  short* W1T    = WoT   + (size_t)5 * 262144;           // L*512*1024
  short* W2T    = W1T   + (size_t)5 * 524288;           // L*1024*512
  short* ffout  = xatt;

  const int M = NB * S;                      // 8192

  wtrans_k<<<2560, 256, 0, stream>>>(Wq, Wk, Wv, Wo, W1, W2, WqkvT, WoT, W1T, W2T);
  wrel_k<<<640, 256, 0, stream>>>(Wq, rel, WqkvT);
  bcat_k<<<(NL * 1664 + 255) / 256, 256, 0, stream>>>(bq, bk, bv, rel, bqkv);
  embed_k<<<(size_t)M * D / 256, 256, 0, stream>>>(x, tok, hb);

  for (int l = 0; l < NL; l++){
    // fused QKV+qrel: q,k -> qkv[M][1024]; v -> vT (transposed bounce); qrel -> qrelb
    mm_nt<128, 128, 5, 32><<<dim3(13, 64, 1), 256, 0, stream>>>(
        hb, 512, WqkvT + (size_t)l * 851968, 512, bqkv + l * 1664,
        qkv, 1024, nullptr, vT, qrelb, 512, 0, 0, 0);

    // scores -> exp -> p (unnormalized, zeros above diagonal), 64x128 tiles
    mm_nt<64, 128, 3, 64><<<dim3(4, 8, NB), 256, 0, stream>>>(
        qkv, 1024, qkv + 512, 1024, nullptr,
        p, 512, qrelb, nullptr, nullptr, 512,
        (long)S * 1024, (long)S * 1024, (long)S * S);

    // PV + row-sum normalize, 64x128 tiles, K clipped at diagonal
    mm_nt<64, 128, 4, 64><<<dim3(4, 8, NB), 256, 0, stream>>>(
        p, 512, vT, 512, nullptr,
        ctx, 512, nullptr, nullptr, nullptr, 512,
        (long)S * S, (long)D * S, (long)S * D);

    mm_nt<128, 64, 1, 64><<<dim3(8, 64, 1), 256, 0, stream>>>(
        ctx, 512, WoT + (size_t)l * 262144, 512, bo + l * 512,
        xatt, 512, nullptr, nullptr, nullptr, 512, 0, 0, 0);
    add_ln_k<0><<<M / 4, 256, 0, stream>>>(hb, xatt, g1 + l * 512, be1 + l * 512, nullptr);

    mm_nt<128, 128, 2, 32><<<dim3(8, 64, 1), 256, 0, stream>>>(
        hb, 512, W1T + (size_t)l * 524288, 512, b1 + l * 1024,
        ffmid, 1024, nullptr, nullptr, nullptr, 512, 0, 0, 0);
    mm_nt<128, 64, 1, 64><<<dim3(8, 64, 1), 256, 0, stream>>>(
        ffmid, 1024, W2T + (size_t)l * 524288, 1024, b2 + l * 512,
        ffout, 512, nullptr, nullptr, nullptr, 1024, 0, 0, 0);
    if (l < NL - 1)
      add_ln_k<0><<<M / 4, 256, 0, stream>>>(hb, ffout, g2 + l * 512, be2 + l * 512, nullptr);
    else
      add_ln_k<1><<<M / 4, 256, 0, stream>>>(hb, ffout, g2 + l * 512, be2 + l * 512, h);
  }
}